// Round 1
// baseline (1673.198 us; speedup 1.0000x reference)
//
#include <hip/hip_runtime.h>

// Problem constants
#define T_  4096
#define B_  64
#define DI_ 64
#define DH_ 512
#define DO_ 64
#define L_  64          // chunk length
#define C_  (T_ / L_)   // 64 chunks

#define HSTRIDE 520     // LDS row stride (words) for h tile: (8s+k)%32 banks -> 2-way max

// ---------------------------------------------------------------------------
// Kernel 1: per-chunk weighted reduction r_c[b][hid] = sum_s a^{L-1-s} * (x_s @ b)[hid]
// grid (C_, B_), block 512 (one thread per hid).
// x addresses are wave-uniform -> scalar loads (SGPR); b column held in VGPRs.
// ---------------------------------------------------------------------------
__global__ __launch_bounds__(512) void k_chunk_r(
    const float* __restrict__ x, const float* __restrict__ bmat,
    const float* __restrict__ a, float* __restrict__ r)
{
    const int c   = blockIdx.x;
    const int bb  = blockIdx.y;
    const int hid = threadIdx.x;

    const float* xp = x + ((size_t)c * L_ * B_ + bb) * DI_;

    float breg[DI_];
#pragma unroll
    for (int i = 0; i < DI_; ++i) breg[i] = bmat[i * DH_ + hid];

    const float ah = a[hid];
    float racc = 0.f;

    for (int s = 0; s < L_; ++s) {
        const float* xs = xp + (size_t)s * B_ * DI_;
        float s0 = 0.f, s1 = 0.f, s2 = 0.f, s3 = 0.f;
#pragma unroll
        for (int i = 0; i < DI_; i += 4) {
            s0 = fmaf(xs[i + 0], breg[i + 0], s0);
            s1 = fmaf(xs[i + 1], breg[i + 1], s1);
            s2 = fmaf(xs[i + 2], breg[i + 2], s2);
            s3 = fmaf(xs[i + 3], breg[i + 3], s3);
        }
        const float xb = (s0 + s1) + (s2 + s3);
        racc = fmaf(racc, ah, xb);   // r = a*r + xb_s  => sum_s a^{L-1-s} xb_s
    }
    r[((size_t)c * B_ + bb) * DH_ + hid] = racc;
}

// ---------------------------------------------------------------------------
// Kernel 2: sequential scan over chunk aggregates.
// H_{c+1} = a^L * H_c + r_c ; stores per-chunk START state Hst[c], writes h_final.
// grid (B_), block 512.
// ---------------------------------------------------------------------------
__global__ __launch_bounds__(512) void k_scan(
    const float* __restrict__ h0, const float* __restrict__ a,
    const float* __restrict__ r, float* __restrict__ Hst,
    float* __restrict__ hfin)
{
    const int bb  = blockIdx.x;
    const int hid = threadIdx.x;

    float h  = h0[bb * DH_ + hid];
    float aL = a[hid];
#pragma unroll
    for (int q = 0; q < 6; ++q) aL = aL * aL;   // a^64

    for (int c = 0; c < C_; ++c) {
        const size_t off = ((size_t)c * B_ + bb) * DH_ + hid;
        Hst[off] = h;                 // state BEFORE chunk c
        h = fmaf(h, aL, r[off]);
    }
    hfin[bb * DH_ + hid] = h;
}

// ---------------------------------------------------------------------------
// Kernel 3: per-chunk local scan into LDS, then y = h @ c.
// grid (C_, B_), block 512, dynamic LDS = L_*HSTRIDE*4 bytes (~130 KB).
// Phase i : thread = hid, recompute xb (scalar x loads), h = a*h + xb, store to LDS.
// Phase ii: thread = (s = tid>>3, og = tid&7), 8 outputs per thread, c from L1.
// ---------------------------------------------------------------------------
__global__ __launch_bounds__(512) void k_y(
    const float* __restrict__ x, const float* __restrict__ bmat,
    const float* __restrict__ a, const float* __restrict__ cmat,
    const float* __restrict__ Hst, float* __restrict__ y)
{
    extern __shared__ float hlds[];   // [L_][HSTRIDE]

    const int c   = blockIdx.x;
    const int bb  = blockIdx.y;
    const int tid = threadIdx.x;

    // ---- phase i: local scan ----
    {
        const int hid = tid;
        const float* xp = x + ((size_t)c * L_ * B_ + bb) * DI_;

        float breg[DI_];
#pragma unroll
        for (int i = 0; i < DI_; ++i) breg[i] = bmat[i * DH_ + hid];

        const float ah = a[hid];
        float h = Hst[((size_t)c * B_ + bb) * DH_ + hid];

        for (int s = 0; s < L_; ++s) {
            const float* xs = xp + (size_t)s * B_ * DI_;
            float s0 = 0.f, s1 = 0.f, s2 = 0.f, s3 = 0.f;
#pragma unroll
            for (int i = 0; i < DI_; i += 4) {
                s0 = fmaf(xs[i + 0], breg[i + 0], s0);
                s1 = fmaf(xs[i + 1], breg[i + 1], s1);
                s2 = fmaf(xs[i + 2], breg[i + 2], s2);
                s3 = fmaf(xs[i + 3], breg[i + 3], s3);
            }
            h = fmaf(h, ah, (s0 + s1) + (s2 + s3));
            hlds[s * HSTRIDE + hid] = h;      // post-update h (matches reference y)
        }
    }
    __syncthreads();

    // ---- phase ii: y[t0+s][bb][o] = sum_hid h[s][hid] * c[hid][o] ----
    {
        const int s  = tid >> 3;
        const int og = tid & 7;

        float acc0 = 0.f, acc1 = 0.f, acc2 = 0.f, acc3 = 0.f;
        float acc4 = 0.f, acc5 = 0.f, acc6 = 0.f, acc7 = 0.f;

        const float* hrow = &hlds[s * HSTRIDE];
        const float* cbase = cmat + og * 8;

        for (int k = 0; k < DH_; k += 4) {
            const float4 hv = *(const float4*)&hrow[k];
#pragma unroll
            for (int kk = 0; kk < 4; ++kk) {
                const float hk = (kk == 0) ? hv.x : (kk == 1) ? hv.y : (kk == 2) ? hv.z : hv.w;
                const float4 c0 = *(const float4*)&cbase[(k + kk) * DO_];
                const float4 c1 = *(const float4*)&cbase[(k + kk) * DO_ + 4];
                acc0 = fmaf(hk, c0.x, acc0);
                acc1 = fmaf(hk, c0.y, acc1);
                acc2 = fmaf(hk, c0.z, acc2);
                acc3 = fmaf(hk, c0.w, acc3);
                acc4 = fmaf(hk, c1.x, acc4);
                acc5 = fmaf(hk, c1.y, acc5);
                acc6 = fmaf(hk, c1.z, acc6);
                acc7 = fmaf(hk, c1.w, acc7);
            }
        }

        const int t = c * L_ + s;
        float* yp = y + ((size_t)t * B_ + bb) * DO_ + og * 8;
        *(float4*)(yp)     = make_float4(acc0, acc1, acc2, acc3);
        *(float4*)(yp + 4) = make_float4(acc4, acc5, acc6, acc7);
    }
}

// ---------------------------------------------------------------------------
extern "C" void kernel_launch(void* const* d_in, const int* in_sizes, int n_in,
                              void* d_out, int out_size, void* d_ws, size_t ws_size,
                              hipStream_t stream) {
    (void)in_sizes; (void)n_in; (void)out_size; (void)ws_size;

    const float* h0 = (const float*)d_in[0];   // [B, DH]
    const float* x  = (const float*)d_in[1];   // [T, B, DI]
    const float* a  = (const float*)d_in[2];   // [DH]
    const float* b  = (const float*)d_in[3];   // [DI, DH]
    const float* cm = (const float*)d_in[4];   // [DH, DO]

    float* out  = (float*)d_out;
    float* hfin = out;                         // [B, DH]
    float* y    = out + (size_t)B_ * DH_;      // [T, B, DO]

    float* r   = (float*)d_ws;                 // [C, B, DH]
    float* Hst = r + (size_t)C_ * B_ * DH_;    // [C, B, DH]

    k_chunk_r<<<dim3(C_, B_), 512, 0, stream>>>(x, b, a, r);
    k_scan<<<dim3(B_), 512, 0, stream>>>(h0, a, r, Hst, hfin);
    k_y<<<dim3(C_, B_), 512, (size_t)L_ * HSTRIDE * sizeof(float), stream>>>(x, b, a, cm, Hst, y);
}

// Round 2
// 921.029 us; speedup vs baseline: 1.8167x; 1.8167x over previous
//
#include <hip/hip_runtime.h>
#include <stdint.h>

// Problem constants
#define T_  4096
#define B_  64
#define DI_ 64
#define DH_ 512
#define DO_ 64
#define L_  64          // chunk length
#define C_  (T_ / L_)   // 64 chunks

#define HSTR 516        // u32 stride per s-row in LDS (mult of 4 -> 16B aligned rows)

typedef __attribute__((ext_vector_type(8))) short bf16x8;
typedef __attribute__((ext_vector_type(4))) float f32x4;

__device__ inline unsigned short f2b_rne(float f) {
    unsigned u = __float_as_uint(f);
    return (unsigned short)((u + 0x7fffu + ((u >> 16) & 1u)) >> 16);
}
// pack float into (hi bf16 | lo bf16 << 16); hi+lo reconstructs ~16-bit mantissa
__device__ inline unsigned pack_hilo(float h) {
    unsigned short hi = f2b_rne(h);
    float hif = __uint_as_float(((unsigned)hi) << 16);
    unsigned short lo = f2b_rne(h - hif);
    return (unsigned)hi | (((unsigned)lo) << 16);
}

// ---------------------------------------------------------------------------
// Kernel 1: per-chunk weighted reduction r_c[b][hid] = sum_s a^{L-1-s} * (x_s @ b)[hid]
// grid (C_, B_), block 512 (one thread per hid). x loads are block-uniform -> scalar.
// ---------------------------------------------------------------------------
__global__ __launch_bounds__(512) void k_chunk_r(
    const float* __restrict__ x, const float* __restrict__ bmat,
    const float* __restrict__ a, float* __restrict__ r)
{
    const int c   = blockIdx.x;
    const int bb  = blockIdx.y;
    const int hid = threadIdx.x;

    const float* xp = x + ((size_t)c * L_ * B_ + bb) * DI_;

    float breg[DI_];
#pragma unroll
    for (int i = 0; i < DI_; ++i) breg[i] = bmat[i * DH_ + hid];

    const float ah = a[hid];
    float racc = 0.f;

    for (int s = 0; s < L_; ++s) {
        const float* xs = xp + (size_t)s * B_ * DI_;
        float s0 = 0.f, s1 = 0.f, s2 = 0.f, s3 = 0.f;
#pragma unroll
        for (int i = 0; i < DI_; i += 4) {
            s0 = fmaf(xs[i + 0], breg[i + 0], s0);
            s1 = fmaf(xs[i + 1], breg[i + 1], s1);
            s2 = fmaf(xs[i + 2], breg[i + 2], s2);
            s3 = fmaf(xs[i + 3], breg[i + 3], s3);
        }
        racc = fmaf(racc, ah, (s0 + s1) + (s2 + s3));
    }
    r[((size_t)c * B_ + bb) * DH_ + hid] = racc;
}

// ---------------------------------------------------------------------------
// Kernel 2: sequential scan over chunk aggregates -> per-chunk start states + h_final.
// ---------------------------------------------------------------------------
__global__ __launch_bounds__(512) void k_scan(
    const float* __restrict__ h0, const float* __restrict__ a,
    const float* __restrict__ r, float* __restrict__ Hst,
    float* __restrict__ hfin)
{
    const int bb  = blockIdx.x;
    const int hid = threadIdx.x;

    float h  = h0[bb * DH_ + hid];
    float aL = a[hid];
#pragma unroll
    for (int q = 0; q < 6; ++q) aL = aL * aL;   // a^64

    for (int c = 0; c < C_; ++c) {
        const size_t off = ((size_t)c * B_ + bb) * DH_ + hid;
        Hst[off] = h;
        h = fmaf(h, aL, r[off]);
    }
    hfin[bb * DH_ + hid] = h;
}

// ---------------------------------------------------------------------------
// Kernel 3: phase i = local scan (VALU, h stored to LDS as packed hi/lo bf16),
//           phase ii = y = h @ c via MFMA 16x16x32 bf16 with hi/lo split
//           (3 terms: hi*hi + hi*lo + lo*hi  ~= fp32 accuracy).
// grid (C_, B_), block 512 (8 waves), dynamic LDS = 64*HSTR*4 bytes (~129 KB).
// Wave w: M-tile m = w>>1 (16 s-rows), N-half o0 = (w&1)*32 (2 N-tiles of 16).
// ---------------------------------------------------------------------------
__global__ __launch_bounds__(512) void k_y(
    const float* __restrict__ x, const float* __restrict__ bmat,
    const float* __restrict__ a, const float* __restrict__ cmat,
    const float* __restrict__ Hst, float* __restrict__ y)
{
    extern __shared__ unsigned hlds[];   // [L_][HSTR] packed hi|lo bf16

    const int c   = blockIdx.x;
    const int bb  = blockIdx.y;
    const int tid = threadIdx.x;

    // ---- phase i: local scan, recompute xb with block-uniform x loads ----
    {
        const int hid = tid;
        const float* xp = x + ((size_t)c * L_ * B_ + bb) * DI_;

        float breg[DI_];
#pragma unroll
        for (int i = 0; i < DI_; ++i) breg[i] = bmat[i * DH_ + hid];

        const float ah = a[hid];
        float h = Hst[((size_t)c * B_ + bb) * DH_ + hid];

        for (int s = 0; s < L_; ++s) {
            const float* xs = xp + (size_t)s * B_ * DI_;
            float s0 = 0.f, s1 = 0.f, s2 = 0.f, s3 = 0.f;
#pragma unroll
            for (int i = 0; i < DI_; i += 4) {
                s0 = fmaf(xs[i + 0], breg[i + 0], s0);
                s1 = fmaf(xs[i + 1], breg[i + 1], s1);
                s2 = fmaf(xs[i + 2], breg[i + 2], s2);
                s3 = fmaf(xs[i + 3], breg[i + 3], s3);
            }
            h = fmaf(h, ah, (s0 + s1) + (s2 + s3));
            hlds[s * HSTR + hid] = pack_hilo(h);
        }
    }
    __syncthreads();

    // ---- phase ii: y[c*64+s][bb][o] = sum_h h[s][h] * c[h][o] via MFMA ----
    {
        const int lane = tid & 63;
        const int w    = tid >> 6;
        const int m    = w >> 1;            // M-tile (s rows m*16..m*16+15)
        const int o0   = (w & 1) * 32;      // N-half base
        const int lrow = lane & 15;
        const int kgrp = lane >> 4;         // 0..3 (k sub-group of 8)

        f32x4 acc0 = {0.f, 0.f, 0.f, 0.f};
        f32x4 acc1 = {0.f, 0.f, 0.f, 0.f};

        const unsigned* abase = &hlds[(m * 16 + lrow) * HSTR];

        for (int kf = 0; kf < 16; ++kf) {
            const int k0 = kf * 32 + kgrp * 8;

            // A-frag: 8 consecutive packed h values (row = s, k = h)
            uint4 w0 = *(const uint4*)&abase[k0];
            uint4 w1 = *(const uint4*)&abase[k0 + 4];
            unsigned uu[8] = {w0.x, w0.y, w0.z, w0.w, w1.x, w1.y, w1.z, w1.w};
            bf16x8 ahi, alo;
#pragma unroll
            for (int j = 0; j < 8; ++j) {
                ahi[j] = (short)(uu[j] & 0xffffu);
                alo[j] = (short)(uu[j] >> 16);
            }

#pragma unroll
            for (int nt = 0; nt < 2; ++nt) {
                bf16x8 bhi, blo;
#pragma unroll
                for (int j = 0; j < 8; ++j) {
                    float cv = cmat[(size_t)(k0 + j) * DO_ + o0 + nt * 16 + lrow];
                    unsigned short h16 = f2b_rne(cv);
                    bhi[j] = (short)h16;
                    blo[j] = (short)f2b_rne(cv - __uint_as_float(((unsigned)h16) << 16));
                }
                if (nt == 0) {
                    acc0 = __builtin_amdgcn_mfma_f32_16x16x32_bf16(ahi, bhi, acc0, 0, 0, 0);
                    acc0 = __builtin_amdgcn_mfma_f32_16x16x32_bf16(ahi, blo, acc0, 0, 0, 0);
                    acc0 = __builtin_amdgcn_mfma_f32_16x16x32_bf16(alo, bhi, acc0, 0, 0, 0);
                } else {
                    acc1 = __builtin_amdgcn_mfma_f32_16x16x32_bf16(ahi, bhi, acc1, 0, 0, 0);
                    acc1 = __builtin_amdgcn_mfma_f32_16x16x32_bf16(ahi, blo, acc1, 0, 0, 0);
                    acc1 = __builtin_amdgcn_mfma_f32_16x16x32_bf16(alo, bhi, acc1, 0, 0, 0);
                }
            }
        }

        // store: D layout col=lane&15 (o), row=(lane>>4)*4+reg (s)
#pragma unroll
        for (int rg = 0; rg < 4; ++rg) {
            const int srow = m * 16 + kgrp * 4 + rg;
            const size_t t = (size_t)c * L_ + srow;
            float* yp = y + (t * B_ + bb) * DO_ + o0 + lrow;
            yp[0]  = acc0[rg];
            yp[16] = acc1[rg];
        }
    }
}

// ---------------------------------------------------------------------------
extern "C" void kernel_launch(void* const* d_in, const int* in_sizes, int n_in,
                              void* d_out, int out_size, void* d_ws, size_t ws_size,
                              hipStream_t stream) {
    (void)in_sizes; (void)n_in; (void)out_size; (void)ws_size;

    const float* h0 = (const float*)d_in[0];   // [B, DH]
    const float* x  = (const float*)d_in[1];   // [T, B, DI]
    const float* a  = (const float*)d_in[2];   // [DH]
    const float* b  = (const float*)d_in[3];   // [DI, DH]
    const float* cm = (const float*)d_in[4];   // [DH, DO]

    float* out  = (float*)d_out;
    float* hfin = out;                         // [B, DH]
    float* y    = out + (size_t)B_ * DH_;      // [T, B, DO]

    float* r   = (float*)d_ws;                 // [C, B, DH]
    float* Hst = r + (size_t)C_ * B_ * DH_;    // [C, B, DH]

    k_chunk_r<<<dim3(C_, B_), 512, 0, stream>>>(x, b, a, r);
    k_scan<<<dim3(B_), 512, 0, stream>>>(h0, a, r, Hst, hfin);
    k_y<<<dim3(C_, B_), 512, (size_t)L_ * HSTR * sizeof(unsigned), stream>>>(x, b, a, cm, Hst, y);
}

// Round 3
// 298.596 us; speedup vs baseline: 5.6036x; 3.0845x over previous
//
#include <hip/hip_runtime.h>
#include <stdint.h>

// Problem constants
#define T_  4096
#define B_  64
#define DI_ 64
#define DH_ 512
#define DO_ 64
#define L_  64          // chunk length
#define C_  (T_ / L_)   // 64 chunks

#define XSTR 68         // x LDS row stride in words (pad 64->68: conflict-free frag reads)

typedef __attribute__((ext_vector_type(8))) short bf16x8;
typedef __attribute__((ext_vector_type(4))) float f32x4;

__device__ inline unsigned short f2b_rne(float f) {
    unsigned u = __float_as_uint(f);
    return (unsigned short)((u + 0x7fffu + ((u >> 16) & 1u)) >> 16);
}
__device__ inline void split2(float v, short& hi, short& lo) {
    unsigned short h = f2b_rne(v);
    hi = (short)h;
    lo = (short)f2b_rne(v - __uint_as_float(((unsigned)h) << 16));
}
// pack float into (hi bf16 | lo bf16 << 16)
__device__ inline unsigned pack_hilo(float v) {
    unsigned short h = f2b_rne(v);
    unsigned short l = f2b_rne(v - __uint_as_float(((unsigned)h) << 16));
    return (unsigned)h | (((unsigned)l) << 16);
}

// ---------------------------------------------------------------------------
// k_frags: one-time pre-swizzle of b [DI x DH] and c [DH x DO] into MFMA
// B-fragment order: [kb][ntile][g][n][j] (hi and lo bf16 separately).
// Wave load address becomes ((kb*NT + nt)*64 + lane)*8 shorts -> 16B/lane coalesced.
// grid 128 x 256 threads = 32768 = entries of each array.
// ---------------------------------------------------------------------------
__global__ __launch_bounds__(256) void k_frags(
    const float* __restrict__ bmat, const float* __restrict__ cmat,
    unsigned short* __restrict__ bhi, unsigned short* __restrict__ blo,
    unsigned short* __restrict__ chi, unsigned short* __restrict__ clo)
{
    const int t = blockIdx.x * 256 + threadIdx.x;   // 0..32767
    {
        // b: kb(2) x nt(32) x g(4) x n(16) x j(8)
        const int j = t & 7, n = (t >> 3) & 15, g = (t >> 7) & 3;
        const int nt = (t >> 9) & 31, kb = (t >> 14) & 1;
        float v = bmat[(size_t)(kb * 32 + g * 8 + j) * DH_ + nt * 16 + n];
        short h, l; split2(v, h, l);
        bhi[t] = (unsigned short)h; blo[t] = (unsigned short)l;
    }
    {
        // c: kb(16) x nt(4) x g(4) x n(16) x j(8)
        const int j = t & 7, n = (t >> 3) & 15, g = (t >> 7) & 3;
        const int nt = (t >> 9) & 3, kb = (t >> 11) & 15;
        float v = cmat[(size_t)(kb * 32 + g * 8 + j) * DO_ + nt * 16 + n];
        short h, l; split2(v, h, l);
        chi[t] = (unsigned short)h; clo[t] = (unsigned short)l;
    }
}

// ---------------------------------------------------------------------------
// k_scan: sequential scan over chunk aggregates -> per-chunk start states + h_final.
// ---------------------------------------------------------------------------
__global__ __launch_bounds__(512) void k_scan(
    const float* __restrict__ h0, const float* __restrict__ a,
    const float* __restrict__ r, float* __restrict__ Hst,
    float* __restrict__ hfin)
{
    const int bb  = blockIdx.x;
    const int hid = threadIdx.x;

    float h  = h0[bb * DH_ + hid];
    float aL = a[hid];
#pragma unroll
    for (int q = 0; q < 6; ++q) aL = aL * aL;   // a^64

    for (int c = 0; c < C_; ++c) {
        const size_t off = ((size_t)c * B_ + bb) * DH_ + hid;
        Hst[off] = h;
        h = fmaf(h, aL, r[off]);
    }
    hfin[bb * DH_ + hid] = h;
}

// ---------------------------------------------------------------------------
// k_main<IS_Y>: per (chunk c, batch bb) block, 512 threads (8 waves).
//  ph1: reg-stage x chunk [64 x 64] f32 into padded LDS (stride XSTR).
//  ph2: xb = x @ b via MFMA 16x16x32 bf16, 3-term hi/lo (~fp32 accurate);
//       write xb f32 into XOR-swizzled LDS tile [64][512] (word ^= (srow&7)<<2).
//  ph3: per-hid serial scan h = a*h + xb (64 fma); IS_Y: repack h as hi|lo u32
//       in place. !IS_Y: h starts at 0, final value is r_c -> write, done.
//  ph4 (IS_Y): y = h @ c via MFMA from swizzled LDS (conflict-free b128 reads)
//       with preconverted c-frags (L2-resident, coalesced).
// LDS: 64*512*4 (h/xb) + 64*68*4 (x) = 148480 B -> 1 block/CU.
// ---------------------------------------------------------------------------
template<bool IS_Y>
__global__ __launch_bounds__(512) void k_main(
    const float* __restrict__ x, const float* __restrict__ a,
    const unsigned short* __restrict__ bhi, const unsigned short* __restrict__ blo,
    const unsigned short* __restrict__ chi, const unsigned short* __restrict__ clo,
    const float* __restrict__ Hst, float* __restrict__ r, float* __restrict__ y)
{
    extern __shared__ unsigned lds[];
    float*    hf = (float*)lds;            // [64][512] xb (f32) then h (packed u32)
    unsigned* hu = lds;
    float*    xs = (float*)(lds + L_ * DH_); // [64][XSTR]

    const int c    = blockIdx.x;
    const int bb   = blockIdx.y;
    const int tid  = threadIdx.x;
    const int lane = tid & 63;
    const int w    = tid >> 6;

    // ---- ph1: stage x chunk ----
    {
        const int row = tid >> 3;           // 0..63 (s)
        const int cc  = (tid & 7) * 8;      // col start (i)
        const float* gp = x + ((size_t)(c * L_ + row) * B_ + bb) * DI_ + cc;
        const float4 v0 = *(const float4*)gp;
        const float4 v1 = *(const float4*)(gp + 4);
        float* dst = xs + row * XSTR + cc;
        *(float4*)dst       = v0;
        *(float4*)(dst + 4) = v1;
    }
    __syncthreads();

    // ---- ph2: xb = x @ b (MFMA) ----
    {
        const int lm = lane & 15;
        const int lg = lane >> 4;

        bf16x8 xh[4][2], xl[4][2];
#pragma unroll
        for (int mt = 0; mt < 4; ++mt)
#pragma unroll
            for (int kb = 0; kb < 2; ++kb) {
                const float* xr = xs + (mt * 16 + lm) * XSTR + kb * 32 + lg * 8;
                const float4 v0 = *(const float4*)xr;
                const float4 v1 = *(const float4*)(xr + 4);
                const float vv[8] = {v0.x, v0.y, v0.z, v0.w, v1.x, v1.y, v1.z, v1.w};
#pragma unroll
                for (int j = 0; j < 8; ++j) {
                    short h, l; split2(vv[j], h, l);
                    xh[mt][kb][j] = h; xl[mt][kb][j] = l;
                }
            }

        f32x4 acc[4][4];
#pragma unroll
        for (int mt = 0; mt < 4; ++mt)
#pragma unroll
            for (int nt = 0; nt < 4; ++nt) acc[mt][nt] = (f32x4){0.f, 0.f, 0.f, 0.f};

#pragma unroll
        for (int ntl = 0; ntl < 4; ++ntl) {
            const int ntg = w * 4 + ntl;
#pragma unroll
            for (int kb = 0; kb < 2; ++kb) {
                const size_t fo = ((size_t)(kb * 32 + ntg) * 64 + lane) * 8;
                const bf16x8 bh = *(const bf16x8*)(bhi + fo);
                const bf16x8 bl = *(const bf16x8*)(blo + fo);
#pragma unroll
                for (int mt = 0; mt < 4; ++mt) {
                    acc[mt][ntl] = __builtin_amdgcn_mfma_f32_16x16x32_bf16(xh[mt][kb], bh, acc[mt][ntl], 0, 0, 0);
                    acc[mt][ntl] = __builtin_amdgcn_mfma_f32_16x16x32_bf16(xl[mt][kb], bh, acc[mt][ntl], 0, 0, 0);
                    acc[mt][ntl] = __builtin_amdgcn_mfma_f32_16x16x32_bf16(xh[mt][kb], bl, acc[mt][ntl], 0, 0, 0);
                }
            }
        }

        // write xb (f32) swizzled: word = srow*512 + (hid ^ ((srow&7)<<2))
#pragma unroll
        for (int mt = 0; mt < 4; ++mt)
#pragma unroll
            for (int ntl = 0; ntl < 4; ++ntl) {
                const int hid = (w * 4 + ntl) * 16 + lm;
#pragma unroll
                for (int rg = 0; rg < 4; ++rg) {
                    const int sr = mt * 16 + lg * 4 + rg;
                    hf[sr * DH_ + (hid ^ ((sr & 7) << 2))] = acc[mt][ntl][rg];
                }
            }
    }
    __syncthreads();

    // ---- ph3: per-hid serial scan ----
    {
        const int hid = tid;
        const float ah = a[hid];
        float h = IS_Y ? Hst[((size_t)c * B_ + bb) * DH_ + hid] : 0.f;
#pragma unroll 8
        for (int s = 0; s < L_; ++s) {
            const int idx = s * DH_ + (hid ^ ((s & 7) << 2));
            h = fmaf(h, ah, hf[idx]);
            if (IS_Y) hu[idx] = pack_hilo(h);
        }
        if (!IS_Y) r[((size_t)c * B_ + bb) * DH_ + hid] = h;
    }
    if (!IS_Y) return;
    __syncthreads();

    // ---- ph4: y = h @ c (MFMA) ----
    {
        const int lm  = lane & 15;
        const int lg  = lane >> 4;
        const int mt  = w >> 1;             // s-tile
        const int oh  = w & 1;              // o half (2 ntiles)
        const int row = mt * 16 + lm;
        const unsigned swz = (unsigned)((row & 7) << 2);
        const unsigned* hrow = hu + row * DH_;

        f32x4 acc0 = {0.f, 0.f, 0.f, 0.f};
        f32x4 acc1 = {0.f, 0.f, 0.f, 0.f};

        for (int kb = 0; kb < 16; ++kb) {
            const int k0 = kb * 32 + lg * 8;
            const uint4 u0 = *(const uint4*)&hrow[(k0 ^ swz)];
            const uint4 u1 = *(const uint4*)&hrow[((k0 + 4) ^ swz)];
            const unsigned uu[8] = {u0.x, u0.y, u0.z, u0.w, u1.x, u1.y, u1.z, u1.w};
            bf16x8 ah8, al8;
#pragma unroll
            for (int j = 0; j < 8; ++j) {
                ah8[j] = (short)(uu[j] & 0xffffu);
                al8[j] = (short)(uu[j] >> 16);
            }
#pragma unroll
            for (int n2 = 0; n2 < 2; ++n2) {
                const size_t fo = ((size_t)(kb * 4 + oh * 2 + n2) * 64 + lane) * 8;
                const bf16x8 ch = *(const bf16x8*)(chi + fo);
                const bf16x8 cl = *(const bf16x8*)(clo + fo);
                if (n2 == 0) {
                    acc0 = __builtin_amdgcn_mfma_f32_16x16x32_bf16(ah8, ch, acc0, 0, 0, 0);
                    acc0 = __builtin_amdgcn_mfma_f32_16x16x32_bf16(al8, ch, acc0, 0, 0, 0);
                    acc0 = __builtin_amdgcn_mfma_f32_16x16x32_bf16(ah8, cl, acc0, 0, 0, 0);
                } else {
                    acc1 = __builtin_amdgcn_mfma_f32_16x16x32_bf16(ah8, ch, acc1, 0, 0, 0);
                    acc1 = __builtin_amdgcn_mfma_f32_16x16x32_bf16(al8, ch, acc1, 0, 0, 0);
                    acc1 = __builtin_amdgcn_mfma_f32_16x16x32_bf16(ah8, cl, acc1, 0, 0, 0);
                }
            }
        }

        // store: D col=lane&15 (o), row=(lane>>4)*4+reg (s)
#pragma unroll
        for (int rg = 0; rg < 4; ++rg) {
            const int sr = mt * 16 + lg * 4 + rg;
            const size_t t = (size_t)c * L_ + sr;
            float* yp = y + (t * B_ + bb) * DO_ + oh * 32 + lm;
            yp[0]  = acc0[rg];
            yp[16] = acc1[rg];
        }
    }
}

// ---------------------------------------------------------------------------
extern "C" void kernel_launch(void* const* d_in, const int* in_sizes, int n_in,
                              void* d_out, int out_size, void* d_ws, size_t ws_size,
                              hipStream_t stream) {
    (void)in_sizes; (void)n_in; (void)out_size; (void)ws_size;

    const float* h0 = (const float*)d_in[0];   // [B, DH]
    const float* x  = (const float*)d_in[1];   // [T, B, DI]
    const float* a  = (const float*)d_in[2];   // [DH]
    const float* bm = (const float*)d_in[3];   // [DI, DH]
    const float* cm = (const float*)d_in[4];   // [DH, DO]

    float* out  = (float*)d_out;
    float* hfin = out;                         // [B, DH]
    float* y    = out + (size_t)B_ * DH_;      // [T, B, DO]

    float* r   = (float*)d_ws;                 // [C, B, DH]  (8 MB)
    float* Hst = r + (size_t)C_ * B_ * DH_;    // [C, B, DH]  (8 MB)
    unsigned short* bhi = (unsigned short*)(Hst + (size_t)C_ * B_ * DH_);
    unsigned short* blo = bhi + 32768;
    unsigned short* chi = blo + 32768;
    unsigned short* clo = chi + 32768;

    const size_t LDSZ = ((size_t)L_ * DH_ + (size_t)L_ * XSTR) * 4;  // 148480 B

    k_frags<<<dim3(128), 256, 0, stream>>>(bm, cm, bhi, blo, chi, clo);
    k_main<false><<<dim3(C_, B_), 512, LDSZ, stream>>>(x, a, bhi, blo, chi, clo, Hst, r, y);
    k_scan<<<dim3(B_), 512, 0, stream>>>(h0, a, r, Hst, hfin);
    k_main<true ><<<dim3(C_, B_), 512, LDSZ, stream>>>(x, a, bhi, blo, chi, clo, Hst, r, y);
}

// Round 4
// 282.831 us; speedup vs baseline: 5.9159x; 1.0557x over previous
//
#include <hip/hip_runtime.h>
#include <stdint.h>

// Problem constants
#define T_  4096
#define B_  64
#define DI_ 64
#define DH_ 512
#define DO_ 64
#define L_  64          // chunk length
#define C_  (T_ / L_)   // 64 chunks

typedef __attribute__((ext_vector_type(8))) short bf16x8;
typedef __attribute__((ext_vector_type(4))) float f32x4;

union U8 { uint4 q; bf16x8 v; };

__device__ inline unsigned short f2b_rne(float f) {
    unsigned u = __float_as_uint(f);
    return (unsigned short)((u + 0x7fffu + ((u >> 16) & 1u)) >> 16);
}
__device__ inline void split2(float v, short& hi, short& lo) {  // rne+rne (weights, one-time)
    unsigned short h = f2b_rne(v);
    hi = (short)h;
    lo = (short)f2b_rne(v - __uint_as_float(((unsigned)h) << 16));
}

// trunc-split 8 f32 -> hi bf16x8 + lo bf16x8 (hi=trunc, lo=remainder trunc; err<=2^-16)
__device__ inline void trunc_split8(const float4 v0, const float4 v1, U8& hi, U8& lo) {
    const unsigned u0 = __float_as_uint(v0.x), u1 = __float_as_uint(v0.y),
                   u2 = __float_as_uint(v0.z), u3 = __float_as_uint(v0.w),
                   u4 = __float_as_uint(v1.x), u5 = __float_as_uint(v1.y),
                   u6 = __float_as_uint(v1.z), u7 = __float_as_uint(v1.w);
    hi.q.x = __builtin_amdgcn_perm(u1, u0, 0x07060302u);
    hi.q.y = __builtin_amdgcn_perm(u3, u2, 0x07060302u);
    hi.q.z = __builtin_amdgcn_perm(u5, u4, 0x07060302u);
    hi.q.w = __builtin_amdgcn_perm(u7, u6, 0x07060302u);
    const unsigned l0 = __float_as_uint(v0.x - __uint_as_float(u0 & 0xffff0000u));
    const unsigned l1 = __float_as_uint(v0.y - __uint_as_float(u1 & 0xffff0000u));
    const unsigned l2 = __float_as_uint(v0.z - __uint_as_float(u2 & 0xffff0000u));
    const unsigned l3 = __float_as_uint(v0.w - __uint_as_float(u3 & 0xffff0000u));
    const unsigned l4 = __float_as_uint(v1.x - __uint_as_float(u4 & 0xffff0000u));
    const unsigned l5 = __float_as_uint(v1.y - __uint_as_float(u5 & 0xffff0000u));
    const unsigned l6 = __float_as_uint(v1.z - __uint_as_float(u6 & 0xffff0000u));
    const unsigned l7 = __float_as_uint(v1.w - __uint_as_float(u7 & 0xffff0000u));
    lo.q.x = __builtin_amdgcn_perm(l1, l0, 0x07060302u);
    lo.q.y = __builtin_amdgcn_perm(l3, l2, 0x07060302u);
    lo.q.z = __builtin_amdgcn_perm(l5, l4, 0x07060302u);
    lo.q.w = __builtin_amdgcn_perm(l7, l6, 0x07060302u);
}

// ---------------------------------------------------------------------------
// k_frags: b -> hi/lo rne frags [2kb][32nt][64lane][8]; c -> single rne frags
// [16kb][4nt][64lane][8]. grid 128 x 256.
// ---------------------------------------------------------------------------
__global__ __launch_bounds__(256) void k_frags(
    const float* __restrict__ bmat, const float* __restrict__ cmat,
    unsigned short* __restrict__ bhi, unsigned short* __restrict__ blo,
    unsigned short* __restrict__ cfr)
{
    const int t = blockIdx.x * 256 + threadIdx.x;   // 0..32767
    {
        const int j = t & 7, n = (t >> 3) & 15, g = (t >> 7) & 3;
        const int nt = (t >> 9) & 31, kb = (t >> 14) & 1;
        float v = bmat[(size_t)(kb * 32 + g * 8 + j) * DH_ + nt * 16 + n];
        short h, l; split2(v, h, l);
        bhi[t] = (unsigned short)h; blo[t] = (unsigned short)l;
    }
    {
        const int j = t & 7, n = (t >> 3) & 15, g = (t >> 7) & 3;
        const int nt = (t >> 9) & 3, kb = (t >> 11) & 15;
        float v = cmat[(size_t)(kb * 32 + g * 8 + j) * DO_ + nt * 16 + n];
        cfr[t] = f2b_rne(v);
    }
}

// ---------------------------------------------------------------------------
// k_scan: sequential scan over chunk aggregates, IN PLACE (r becomes Hst).
// ---------------------------------------------------------------------------
__global__ __launch_bounds__(512) void k_scan(
    const float* __restrict__ h0, const float* __restrict__ a,
    float* __restrict__ r, float* __restrict__ hfin)
{
    const int bb  = blockIdx.x;
    const int hid = threadIdx.x;

    float h  = h0[bb * DH_ + hid];
    float aL = a[hid];
#pragma unroll
    for (int q = 0; q < 6; ++q) aL = aL * aL;   // a^64

    for (int c = 0; c < C_; ++c) {
        const size_t off = ((size_t)c * B_ + bb) * DH_ + hid;
        const float rv = r[off];
        r[off] = h;                 // Hst[c] = state BEFORE chunk c
        h = fmaf(h, aL, rv);
    }
    hfin[bb * DH_ + hid] = h;
}

// ---------------------------------------------------------------------------
// k_main<IS_Y>: per (chunk, batch) block, 512 threads, LDS 128 KB.
//  ph2: x-frags direct from global (trunc-split hi/lo), xb = x@b via 3-term
//       MFMA; write xb f32 to LDS [hid][s] (b128, block-of-4 XOR swizzle).
//  ph3: thread=hid reads its 64-f32 row (16 b128) into regs; (IS_Y) barrier,
//       then serial scan; IS_Y packs h to bf16 rne into [s][hid^((s&7)<<3)]
//       (overwrites xb region — safe post-barrier). !IS_Y writes r.
//  ph4 (IS_Y): y = h @ c, single-term bf16 MFMA; A = 1 b128/kb from LDS,
//       B = preconverted c-frags (L1/L2 resident).
// ---------------------------------------------------------------------------
template<bool IS_Y>
__global__ __launch_bounds__(512, 2) void k_main(
    const float* __restrict__ x, const float* __restrict__ a,
    const unsigned short* __restrict__ bhi, const unsigned short* __restrict__ blo,
    const unsigned short* __restrict__ cfr,
    const float* __restrict__ Hst, float* __restrict__ r, float* __restrict__ y)
{
    extern __shared__ unsigned lds[];              // 128 KB
    float* xbf = (float*)lds;                      // [512 hid][16 blk of 4] swizzled
    unsigned short* hb = (unsigned short*)lds;     // [64 s][512 hid'] (first 64 KB)

    const int c    = blockIdx.x;
    const int bb   = blockIdx.y;
    const int tid  = threadIdx.x;
    const int lane = tid & 63;
    const int w    = tid >> 6;
    const int lm   = lane & 15;
    const int lg   = lane >> 4;

    // ---- ph2: xb = x @ b ----
    {
        U8 xh[4][2], xl[4][2];
#pragma unroll
        for (int mt = 0; mt < 4; ++mt)
#pragma unroll
            for (int kb = 0; kb < 2; ++kb) {
                const float* gp = x + (((size_t)(c * 64 + mt * 16 + lm)) * 64 + bb) * 64 + kb * 32 + lg * 8;
                const float4 v0 = *(const float4*)gp;
                const float4 v1 = *(const float4*)(gp + 4);
                trunc_split8(v0, v1, xh[mt][kb], xl[mt][kb]);
            }

        f32x4 acc[4][4];
#pragma unroll
        for (int mt = 0; mt < 4; ++mt)
#pragma unroll
            for (int nt = 0; nt < 4; ++nt) acc[mt][nt] = (f32x4){0.f, 0.f, 0.f, 0.f};

#pragma unroll
        for (int ntl = 0; ntl < 4; ++ntl) {
            const int ntg = w * 4 + ntl;
#pragma unroll
            for (int kb = 0; kb < 2; ++kb) {
                const size_t fo = ((size_t)(kb * 32 + ntg) * 64 + lane) * 8;
                const bf16x8 bh = *(const bf16x8*)(bhi + fo);
                const bf16x8 bl = *(const bf16x8*)(blo + fo);
#pragma unroll
                for (int mt = 0; mt < 4; ++mt) {
                    acc[mt][ntl] = __builtin_amdgcn_mfma_f32_16x16x32_bf16(xh[mt][kb].v, bh, acc[mt][ntl], 0, 0, 0);
                    acc[mt][ntl] = __builtin_amdgcn_mfma_f32_16x16x32_bf16(xl[mt][kb].v, bh, acc[mt][ntl], 0, 0, 0);
                    acc[mt][ntl] = __builtin_amdgcn_mfma_f32_16x16x32_bf16(xh[mt][kb].v, bl, acc[mt][ntl], 0, 0, 0);
                }
            }
        }

        // write xb [hid][s], b128, physical s-block = (mt*4+lg) ^ (hid&7)
#pragma unroll
        for (int mt = 0; mt < 4; ++mt)
#pragma unroll
            for (int ntl = 0; ntl < 4; ++ntl) {
                const int hid  = (w * 4 + ntl) * 16 + lm;
                const int phys = (mt * 4 + lg) ^ (hid & 7);
                *(f32x4*)(xbf + (size_t)hid * 64 + phys * 4) = acc[mt][ntl];
            }
    }
    __syncthreads();

    // ---- ph3: per-hid serial scan (row in registers) ----
    {
        const int hid = tid;
        uint4 q[16];
#pragma unroll
        for (int ls4 = 0; ls4 < 16; ++ls4)
            q[ls4] = *(const uint4*)(xbf + (size_t)hid * 64 + ((ls4 ^ (hid & 7)) << 2));

        if (IS_Y) __syncthreads();   // all rows in regs before hb overwrites xb

        const float ah = a[hid];
        float h = IS_Y ? Hst[((size_t)c * B_ + bb) * DH_ + hid] : 0.f;

#define STEP(val, sidx)                                                        \
        {                                                                      \
            h = fmaf(h, ah, __uint_as_float(val));                             \
            if (IS_Y) hb[(sidx) * 512 + (hid ^ (((sidx) & 7) << 3))] = f2b_rne(h); \
        }
#pragma unroll
        for (int s4 = 0; s4 < 16; ++s4) {
            const uint4 qq = q[s4];
            STEP(qq.x, s4 * 4 + 0)
            STEP(qq.y, s4 * 4 + 1)
            STEP(qq.z, s4 * 4 + 2)
            STEP(qq.w, s4 * 4 + 3)
        }
#undef STEP

        if (!IS_Y) { r[((size_t)c * B_ + bb) * DH_ + hid] = h; return; }
    }
    __syncthreads();

    // ---- ph4: y = h @ c (single-term bf16 MFMA) ----
    {
        const int mt  = w >> 1;
        const int oh  = w & 1;
        const int row = mt * 16 + lm;
        const int sw  = (row & 7) << 3;
        const unsigned short* hrow = hb + row * 512;

        f32x4 acc0 = {0.f, 0.f, 0.f, 0.f};
        f32x4 acc1 = {0.f, 0.f, 0.f, 0.f};

#pragma unroll
        for (int kb = 0; kb < 16; ++kb) {
            const int k0 = kb * 32 + lg * 8;
            const bf16x8 af = *(const bf16x8*)(hrow + (k0 ^ sw));
            const bf16x8 c0 = *(const bf16x8*)(cfr + ((size_t)(kb * 4 + oh * 2 + 0) * 64 + lane) * 8);
            const bf16x8 c1 = *(const bf16x8*)(cfr + ((size_t)(kb * 4 + oh * 2 + 1) * 64 + lane) * 8);
            acc0 = __builtin_amdgcn_mfma_f32_16x16x32_bf16(af, c0, acc0, 0, 0, 0);
            acc1 = __builtin_amdgcn_mfma_f32_16x16x32_bf16(af, c1, acc1, 0, 0, 0);
        }

        // D layout: col = lane&15 (o), row = (lane>>4)*4 + reg (s)
#pragma unroll
        for (int rg = 0; rg < 4; ++rg) {
            const int sr = mt * 16 + lg * 4 + rg;
            float* yp = y + (((size_t)(c * 64 + sr)) * 64 + bb) * 64 + oh * 32 + lm;
            yp[0]  = acc0[rg];
            yp[16] = acc1[rg];
        }
    }
}

// ---------------------------------------------------------------------------
extern "C" void kernel_launch(void* const* d_in, const int* in_sizes, int n_in,
                              void* d_out, int out_size, void* d_ws, size_t ws_size,
                              hipStream_t stream) {
    (void)in_sizes; (void)n_in; (void)out_size; (void)ws_size;

    const float* h0 = (const float*)d_in[0];   // [B, DH]
    const float* x  = (const float*)d_in[1];   // [T, B, DI]
    const float* a  = (const float*)d_in[2];   // [DH]
    const float* bm = (const float*)d_in[3];   // [DI, DH]
    const float* cm = (const float*)d_in[4];   // [DH, DO]

    float* out  = (float*)d_out;
    float* hfin = out;                         // [B, DH]
    float* y    = out + (size_t)B_ * DH_;      // [T, B, DO]

    float* r = (float*)d_ws;                   // [C, B, DH] (8 MB) — becomes Hst in-place
    unsigned short* bhi = (unsigned short*)(r + (size_t)C_ * B_ * DH_);
    unsigned short* blo = bhi + 32768;
    unsigned short* cfr = blo + 32768;

    const size_t LDSZ = 512 * 64 * 4;          // 131072 B

    k_frags<<<dim3(128), 256, 0, stream>>>(bm, cm, bhi, blo, cfr);
    k_main<false><<<dim3(C_, B_), 512, LDSZ, stream>>>(x, a, bhi, blo, cfr, r, r, y);
    k_scan<<<dim3(B_), 512, 0, stream>>>(h0, a, r, hfin);
    k_main<true ><<<dim3(C_, B_), 512, LDSZ, stream>>>(x, a, bhi, blo, cfr, r, r, y);
}

// Round 5
// 228.659 us; speedup vs baseline: 7.3174x; 1.2369x over previous
//
#include <hip/hip_runtime.h>
#include <stdint.h>

// Problem constants
#define T_  4096
#define B_  64
#define DI_ 64
#define DH_ 512
#define DO_ 64
#define L_  64          // chunk length
#define C_  (T_ / L_)   // 64 chunks

// k_y LDS: xb region 512 rows x 34 dwords (136 B; 64 bf16 + 8 B pad -> bank spread)
#define XBSTR 34

typedef __attribute__((ext_vector_type(8))) short bf16x8;
typedef __attribute__((ext_vector_type(4))) float f32x4;

union U8 { uint4 q; bf16x8 v; };

__device__ inline unsigned short f2b_rne(float f) {
    unsigned u = __float_as_uint(f);
    return (unsigned short)((u + 0x7fffu + ((u >> 16) & 1u)) >> 16);
}
__device__ inline void split2(float v, short& hi, short& lo) {  // rne+rne (weights)
    unsigned short h = f2b_rne(v);
    hi = (short)h;
    lo = (short)f2b_rne(v - __uint_as_float(((unsigned)h) << 16));
}

// trunc-split 8 f32 -> hi bf16x8 + lo bf16x8 (exact to 2^-16, for 3-term MFMA)
__device__ inline void trunc_split8(const float4 v0, const float4 v1, U8& hi, U8& lo) {
    const unsigned u0 = __float_as_uint(v0.x), u1 = __float_as_uint(v0.y),
                   u2 = __float_as_uint(v0.z), u3 = __float_as_uint(v0.w),
                   u4 = __float_as_uint(v1.x), u5 = __float_as_uint(v1.y),
                   u6 = __float_as_uint(v1.z), u7 = __float_as_uint(v1.w);
    hi.q.x = __builtin_amdgcn_perm(u1, u0, 0x07060302u);
    hi.q.y = __builtin_amdgcn_perm(u3, u2, 0x07060302u);
    hi.q.z = __builtin_amdgcn_perm(u5, u4, 0x07060302u);
    hi.q.w = __builtin_amdgcn_perm(u7, u6, 0x07060302u);
    const unsigned l0 = __float_as_uint(v0.x - __uint_as_float(u0 & 0xffff0000u));
    const unsigned l1 = __float_as_uint(v0.y - __uint_as_float(u1 & 0xffff0000u));
    const unsigned l2 = __float_as_uint(v0.z - __uint_as_float(u2 & 0xffff0000u));
    const unsigned l3 = __float_as_uint(v0.w - __uint_as_float(u3 & 0xffff0000u));
    const unsigned l4 = __float_as_uint(v1.x - __uint_as_float(u4 & 0xffff0000u));
    const unsigned l5 = __float_as_uint(v1.y - __uint_as_float(u5 & 0xffff0000u));
    const unsigned l6 = __float_as_uint(v1.z - __uint_as_float(u6 & 0xffff0000u));
    const unsigned l7 = __float_as_uint(v1.w - __uint_as_float(u7 & 0xffff0000u));
    lo.q.x = __builtin_amdgcn_perm(l1, l0, 0x07060302u);
    lo.q.y = __builtin_amdgcn_perm(l3, l2, 0x07060302u);
    lo.q.z = __builtin_amdgcn_perm(l5, l4, 0x07060302u);
    lo.q.w = __builtin_amdgcn_perm(l7, l6, 0x07060302u);
}

// rne-convert 8 f32 -> bf16x8 (single precision term, y-pass x)
__device__ inline void rne8(const float4 v0, const float4 v1, U8& out) {
    const unsigned r0 = f2b_rne(v0.x), r1 = f2b_rne(v0.y),
                   r2 = f2b_rne(v0.z), r3 = f2b_rne(v0.w),
                   r4 = f2b_rne(v1.x), r5 = f2b_rne(v1.y),
                   r6 = f2b_rne(v1.z), r7 = f2b_rne(v1.w);
    out.q.x = r0 | (r1 << 16);
    out.q.y = r2 | (r3 << 16);
    out.q.z = r4 | (r5 << 16);
    out.q.w = r6 | (r7 << 16);
}

// ---------------------------------------------------------------------------
// k_frags: b -> hi/lo rne frags [2kb][32nt][64lane][8]; c -> single rne frags
// [16kb][4nt][64lane][8]. grid 128 x 256.
// ---------------------------------------------------------------------------
__global__ __launch_bounds__(256) void k_frags(
    const float* __restrict__ bmat, const float* __restrict__ cmat,
    unsigned short* __restrict__ bhi, unsigned short* __restrict__ blo,
    unsigned short* __restrict__ cfr)
{
    const int t = blockIdx.x * 256 + threadIdx.x;   // 0..32767
    {
        const int j = t & 7, n = (t >> 3) & 15, g = (t >> 7) & 3;
        const int nt = (t >> 9) & 31, kb = (t >> 14) & 1;
        float v = bmat[(size_t)(kb * 32 + g * 8 + j) * DH_ + nt * 16 + n];
        short h, l; split2(v, h, l);
        bhi[t] = (unsigned short)h; blo[t] = (unsigned short)l;
    }
    {
        const int j = t & 7, n = (t >> 3) & 15, g = (t >> 7) & 3;
        const int nt = (t >> 9) & 3, kb = (t >> 11) & 15;
        float v = cmat[(size_t)(kb * 32 + g * 8 + j) * DO_ + nt * 16 + n];
        cfr[t] = f2b_rne(v);
    }
}

// ---------------------------------------------------------------------------
// k_r: per (chunk, batch) block: xb = x @ b (3-term hi/lo MFMA, ~fp32), then
// r_c[hid] = sum_s a^{63-s} xb_s entirely in registers:
//  per lane (owns s = mt*16+lg*4+{0..3} for 16 hid cols): weighted 4-run
//  aggregate R, pre-scale by a4^{-lg}, butterfly-sum across lg (shfl_xor 16/32),
//  serial combine over mt. No LDS, no barriers.
// ---------------------------------------------------------------------------
__global__ __launch_bounds__(512, 2) void k_r(
    const float* __restrict__ x, const float* __restrict__ a,
    const unsigned short* __restrict__ bhi, const unsigned short* __restrict__ blo,
    float* __restrict__ r)
{
    const int c    = blockIdx.x;
    const int bb   = blockIdx.y;
    const int tid  = threadIdx.x;
    const int lane = tid & 63;
    const int w    = tid >> 6;
    const int lm   = lane & 15;
    const int lg   = lane >> 4;

    U8 xh[4][2], xl[4][2];
#pragma unroll
    for (int mt = 0; mt < 4; ++mt)
#pragma unroll
        for (int kb = 0; kb < 2; ++kb) {
            const float* gp = x + (((size_t)(c * 64 + mt * 16 + lm)) * 64 + bb) * 64 + kb * 32 + lg * 8;
            const float4 v0 = *(const float4*)gp;
            const float4 v1 = *(const float4*)(gp + 4);
            trunc_split8(v0, v1, xh[mt][kb], xl[mt][kb]);
        }

    f32x4 acc[4][4];
#pragma unroll
    for (int mt = 0; mt < 4; ++mt)
#pragma unroll
        for (int nt = 0; nt < 4; ++nt) acc[mt][nt] = (f32x4){0.f, 0.f, 0.f, 0.f};

#pragma unroll
    for (int ntl = 0; ntl < 4; ++ntl) {
        const int ntg = w * 4 + ntl;
#pragma unroll
        for (int kb = 0; kb < 2; ++kb) {
            const size_t fo = ((size_t)(kb * 32 + ntg) * 64 + lane) * 8;
            const bf16x8 bh = *(const bf16x8*)(bhi + fo);
            const bf16x8 bl = *(const bf16x8*)(blo + fo);
#pragma unroll
            for (int mt = 0; mt < 4; ++mt) {
                acc[mt][ntl] = __builtin_amdgcn_mfma_f32_16x16x32_bf16(xh[mt][kb].v, bh, acc[mt][ntl], 0, 0, 0);
                acc[mt][ntl] = __builtin_amdgcn_mfma_f32_16x16x32_bf16(xl[mt][kb].v, bh, acc[mt][ntl], 0, 0, 0);
                acc[mt][ntl] = __builtin_amdgcn_mfma_f32_16x16x32_bf16(xh[mt][kb].v, bl, acc[mt][ntl], 0, 0, 0);
            }
        }
    }

    // in-register weighted reduction to r_c
#pragma unroll
    for (int ntl = 0; ntl < 4; ++ntl) {
        const int hid = (w * 4 + ntl) * 16 + lm;
        const float ah  = a[hid];
        const float a2  = ah * ah;
        const float a4  = a2 * a2;
        const float a8  = a4 * a4;
        const float a16 = a8 * a8;
        const float w3  = a8 * a4;                       // a^12
        const float inva4 = __builtin_amdgcn_rcpf(a4);
        const float inva8 = inva4 * inva4;
        const float tinv  = ((lg & 1) ? inva4 : 1.0f) * ((lg & 2) ? inva8 : 1.0f);

        float S = 0.f;
#pragma unroll
        for (int mt = 0; mt < 4; ++mt) {
            const f32x4 p = acc[mt][ntl];
            // R = a^3*xb0 + a^2*xb1 + a*xb2 + xb3
            float R = fmaf(fmaf(fmaf(p[0], ah, p[1]), ah, p[2]), ah, p[3]);
            float Rp = R * tinv;                          // pre-scale by a4^-lg
            Rp += __shfl_xor(Rp, 16);                     // sum lg pairs
            Rp += __shfl_xor(Rp, 32);                     // full 4-group sum
            S = fmaf(a16, S, w3 * Rp);                    // S = a^16 S + a^12 * sum
        }
        if (lg == 0) r[((size_t)c * B_ + bb) * DH_ + hid] = S;
    }
}

// ---------------------------------------------------------------------------
// k_scan: sequential scan over chunk aggregates, IN PLACE (r becomes Hst).
// ---------------------------------------------------------------------------
__global__ __launch_bounds__(512) void k_scan(
    const float* __restrict__ h0, const float* __restrict__ a,
    float* __restrict__ r, float* __restrict__ hfin)
{
    const int bb  = blockIdx.x;
    const int hid = threadIdx.x;

    float h  = h0[bb * DH_ + hid];
    float aL = a[hid];
#pragma unroll
    for (int q = 0; q < 6; ++q) aL = aL * aL;   // a^64

    for (int c = 0; c < C_; ++c) {
        const size_t off = ((size_t)c * B_ + bb) * DH_ + hid;
        const float rv = r[off];
        r[off] = h;                 // Hst[c] = state BEFORE chunk c
        h = fmaf(h, aL, rv);
    }
    hfin[bb * DH_ + hid] = h;
}

// ---------------------------------------------------------------------------
// k_y: per (chunk, batch) block, 512 threads, LDS 68 KB -> 2 blocks/CU.
//  ph2: xb = x @ b, SINGLE-term bf16 MFMA (rne x, rne b); pack acc (4 consec s)
//       as 2x u32 bf16-pairs, b64 write to LDS [hid][s] (stride 34 dwords).
//  ph3: thread=hid reads its own wave's rows (wave-local, no barrier) into regs,
//       barrier, serial scan h = a*h + xb, write bf16 h into [s][hid^swz]
//       overlay (same LDS region).
//  ph4: y = h @ c single-term MFMA from swizzled LDS + preconverted c-frags.
// ---------------------------------------------------------------------------
__global__ __launch_bounds__(512, 4) void k_y(
    const float* __restrict__ x, const float* __restrict__ a,
    const unsigned short* __restrict__ bhi, const unsigned short* __restrict__ cfr,
    const float* __restrict__ Hst, float* __restrict__ y)
{
    extern __shared__ unsigned lds[];               // 512*34*4 = 69632 B
    unsigned short* hb = (unsigned short*)lds;      // overlay: [64 s][512 hid^swz]

    const int c    = blockIdx.x;
    const int bb   = blockIdx.y;
    const int tid  = threadIdx.x;
    const int lane = tid & 63;
    const int w    = tid >> 6;
    const int lm   = lane & 15;
    const int lg   = lane >> 4;

    // ---- ph2: xb = x @ b (1-term) ----
    {
        U8 xf[4][2];
#pragma unroll
        for (int mt = 0; mt < 4; ++mt)
#pragma unroll
            for (int kb = 0; kb < 2; ++kb) {
                const float* gp = x + (((size_t)(c * 64 + mt * 16 + lm)) * 64 + bb) * 64 + kb * 32 + lg * 8;
                const float4 v0 = *(const float4*)gp;
                const float4 v1 = *(const float4*)(gp + 4);
                rne8(v0, v1, xf[mt][kb]);
            }

        f32x4 acc[4][4];
#pragma unroll
        for (int mt = 0; mt < 4; ++mt)
#pragma unroll
            for (int nt = 0; nt < 4; ++nt) acc[mt][nt] = (f32x4){0.f, 0.f, 0.f, 0.f};

#pragma unroll
        for (int ntl = 0; ntl < 4; ++ntl) {
            const int ntg = w * 4 + ntl;
#pragma unroll
            for (int kb = 0; kb < 2; ++kb) {
                const size_t fo = ((size_t)(kb * 32 + ntg) * 64 + lane) * 8;
                const bf16x8 bh = *(const bf16x8*)(bhi + fo);
#pragma unroll
                for (int mt = 0; mt < 4; ++mt)
                    acc[mt][ntl] = __builtin_amdgcn_mfma_f32_16x16x32_bf16(xf[mt][kb].v, bh, acc[mt][ntl], 0, 0, 0);
            }
        }

        // pack 4 consecutive s (rg 0..3 at s0 = mt*16+lg*4) into 2 u32, b64 write
#pragma unroll
        for (int mt = 0; mt < 4; ++mt)
#pragma unroll
            for (int ntl = 0; ntl < 4; ++ntl) {
                const int hid = (w * 4 + ntl) * 16 + lm;
                const unsigned p0 = (unsigned)f2b_rne(acc[mt][ntl][0]) | ((unsigned)f2b_rne(acc[mt][ntl][1]) << 16);
                const unsigned p1 = (unsigned)f2b_rne(acc[mt][ntl][2]) | ((unsigned)f2b_rne(acc[mt][ntl][3]) << 16);
                uint2* dst = (uint2*)(lds + (size_t)hid * XBSTR + mt * 8 + lg * 2);
                *dst = make_uint2(p0, p1);
            }
    }
    // NO barrier: each wave's ph3 rows (hid = tid in [64w,64w+64)) were written
    // by this same wave; lgkmcnt ordering suffices.

    // ---- ph3: per-hid serial scan ----
    {
        const int hid = tid;
        uint2 xr[16];
        const unsigned* rowp = lds + (size_t)hid * XBSTR;
#pragma unroll
        for (int j = 0; j < 16; ++j) xr[j] = *(const uint2*)(rowp + 2 * j);

        __syncthreads();   // all xb reads done before h overlay writes

        const float ah = a[hid];
        float h = Hst[((size_t)c * B_ + bb) * DH_ + hid];

#define STEP(xbits, sidx)                                                      \
        {                                                                      \
            h = fmaf(h, ah, __uint_as_float(xbits));                           \
            hb[(sidx) * DH_ + (hid ^ (((sidx) & 7) << 3))] = f2b_rne(h);       \
        }
#pragma unroll
        for (int j = 0; j < 16; ++j) {
            const unsigned ux = xr[j].x, uy = xr[j].y;
            STEP(ux << 16,          j * 4 + 0)
            STEP(ux & 0xffff0000u,  j * 4 + 1)
            STEP(uy << 16,          j * 4 + 2)
            STEP(uy & 0xffff0000u,  j * 4 + 3)
        }
#undef STEP
    }
    __syncthreads();

    // ---- ph4: y = h @ c (single-term bf16 MFMA) ----
    {
        const int mt  = w >> 1;
        const int oh  = w & 1;
        const int row = mt * 16 + lm;
        const int sw  = (row & 7) << 3;
        const unsigned short* hrow = hb + row * DH_;

        f32x4 acc0 = {0.f, 0.f, 0.f, 0.f};
        f32x4 acc1 = {0.f, 0.f, 0.f, 0.f};

#pragma unroll
        for (int kb = 0; kb < 16; ++kb) {
            const int k0 = kb * 32 + lg * 8;
            const bf16x8 af = *(const bf16x8*)(hrow + (k0 ^ sw));
            const bf16x8 c0 = *(const bf16x8*)(cfr + ((size_t)(kb * 4 + oh * 2 + 0) * 64 + lane) * 8);
            const bf16x8 c1 = *(const bf16x8*)(cfr + ((size_t)(kb * 4 + oh * 2 + 1) * 64 + lane) * 8);
            acc0 = __builtin_amdgcn_mfma_f32_16x16x32_bf16(af, c0, acc0, 0, 0, 0);
            acc1 = __builtin_amdgcn_mfma_f32_16x16x32_bf16(af, c1, acc1, 0, 0, 0);
        }

        // D layout: col = lane&15 (o), row = (lane>>4)*4 + reg (s)
#pragma unroll
        for (int rg = 0; rg < 4; ++rg) {
            const int sr = mt * 16 + lg * 4 + rg;
            float* yp = y + (((size_t)(c * 64 + sr)) * 64 + bb) * 64 + oh * 32 + lm;
            yp[0]  = acc0[rg];
            yp[16] = acc1[rg];
        }
    }
}

// ---------------------------------------------------------------------------
extern "C" void kernel_launch(void* const* d_in, const int* in_sizes, int n_in,
                              void* d_out, int out_size, void* d_ws, size_t ws_size,
                              hipStream_t stream) {
    (void)in_sizes; (void)n_in; (void)out_size; (void)ws_size;

    const float* h0 = (const float*)d_in[0];   // [B, DH]
    const float* x  = (const float*)d_in[1];   // [T, B, DI]
    const float* a  = (const float*)d_in[2];   // [DH]
    const float* bm = (const float*)d_in[3];   // [DI, DH]
    const float* cm = (const float*)d_in[4];   // [DH, DO]

    float* out  = (float*)d_out;
    float* hfin = out;                         // [B, DH]
    float* y    = out + (size_t)B_ * DH_;      // [T, B, DO]

    float* r = (float*)d_ws;                   // [C, B, DH] (8 MB) — becomes Hst in-place
    unsigned short* bhi = (unsigned short*)(r + (size_t)C_ * B_ * DH_);
    unsigned short* blo = bhi + 32768;
    unsigned short* cfr = blo + 32768;

    const size_t LDSZ_Y = (size_t)DH_ * XBSTR * 4;   // 69632 B

    k_frags<<<dim3(128), 256, 0, stream>>>(bm, cm, bhi, blo, cfr);
    k_r<<<dim3(C_, B_), 512, 0, stream>>>(x, a, bhi, blo, r);
    k_scan<<<dim3(B_), 512, 0, stream>>>(h0, a, r, hfin);
    k_y<<<dim3(C_, B_), 512, LDSZ_Y, stream>>>(x, a, bhi, cfr, r, y);
}

// Round 6
// 195.981 us; speedup vs baseline: 8.5376x; 1.1667x over previous
//
#include <hip/hip_runtime.h>
#include <stdint.h>

// Problem constants
#define T_  4096
#define B_  64
#define DI_ 64
#define DH_ 512
#define DO_ 64
#define L_  64          // chunk length
#define C_  (T_ / L_)   // 64 chunks

// k_y LDS: xb region 512 rows x 34 dwords (136 B; 64 bf16 + 8 B pad)
#define XBSTR 34

typedef __attribute__((ext_vector_type(8))) short bf16x8;
typedef __attribute__((ext_vector_type(4))) float f32x4;

union U8 { uint4 q; bf16x8 v; };

__device__ inline unsigned short f2b_rne(float f) {
    unsigned u = __float_as_uint(f);
    return (unsigned short)((u + 0x7fffu + ((u >> 16) & 1u)) >> 16);
}
__device__ inline void split2(float v, short& hi, short& lo) {  // rne+rne (weights)
    unsigned short h = f2b_rne(v);
    hi = (short)h;
    lo = (short)f2b_rne(v - __uint_as_float(((unsigned)h) << 16));
}

// rne-convert 8 f32 -> bf16x8
__device__ inline void rne8(const float4 v0, const float4 v1, U8& out) {
    const unsigned r0 = f2b_rne(v0.x), r1 = f2b_rne(v0.y),
                   r2 = f2b_rne(v0.z), r3 = f2b_rne(v0.w),
                   r4 = f2b_rne(v1.x), r5 = f2b_rne(v1.y),
                   r6 = f2b_rne(v1.z), r7 = f2b_rne(v1.w);
    out.q.x = r0 | (r1 << 16);
    out.q.y = r2 | (r3 << 16);
    out.q.z = r4 | (r5 << 16);
    out.q.w = r6 | (r7 << 16);
}

// ---------------------------------------------------------------------------
// k_frags: b -> hi/lo rne frags [2kb][32nt][64lane][8]; c -> single rne frags
// [16kb][4nt][64lane][8]. grid 128 x 256. (blo kept for potential 3-term revert)
// ---------------------------------------------------------------------------
__global__ __launch_bounds__(256) void k_frags(
    const float* __restrict__ bmat, const float* __restrict__ cmat,
    unsigned short* __restrict__ bhi, unsigned short* __restrict__ blo,
    unsigned short* __restrict__ cfr)
{
    const int t = blockIdx.x * 256 + threadIdx.x;   // 0..32767
    {
        const int j = t & 7, n = (t >> 3) & 15, g = (t >> 7) & 3;
        const int nt = (t >> 9) & 31, kb = (t >> 14) & 1;
        float v = bmat[(size_t)(kb * 32 + g * 8 + j) * DH_ + nt * 16 + n];
        short h, l; split2(v, h, l);
        bhi[t] = (unsigned short)h; blo[t] = (unsigned short)l;
    }
    {
        const int j = t & 7, n = (t >> 3) & 15, g = (t >> 7) & 3;
        const int nt = (t >> 9) & 3, kb = (t >> 11) & 15;
        float v = cmat[(size_t)(kb * 32 + g * 8 + j) * DO_ + nt * 16 + n];
        cfr[t] = f2b_rne(v);
    }
}

// ---------------------------------------------------------------------------
// k_r: per (chunk, batch) block: xb = x @ b (1-term bf16 MFMA), then
// r_c[hid] = sum_s a^{63-s} xb_s in registers (weighted shfl butterfly).
// All 16 global loads hoisted up-front -> one latency window per wave.
// No LDS, no barriers.
// ---------------------------------------------------------------------------
__global__ __launch_bounds__(512, 3) void k_r(
    const float* __restrict__ x, const float* __restrict__ a,
    const unsigned short* __restrict__ bhi,
    float* __restrict__ r)
{
    const int c    = blockIdx.x;
    const int bb   = blockIdx.y;
    const int tid  = threadIdx.x;
    const int lane = tid & 63;
    const int w    = tid >> 6;
    const int lm   = lane & 15;
    const int lg   = lane >> 4;

    // b-frag loads first (independent, land directly in operand regs)
    bf16x8 bf[2][4];
#pragma unroll
    for (int kb = 0; kb < 2; ++kb)
#pragma unroll
        for (int ntl = 0; ntl < 4; ++ntl)
            bf[kb][ntl] = *(const bf16x8*)(bhi + ((size_t)(kb * 32 + w * 4 + ntl) * 64 + lane) * 8);

    // x loads (8 x 32B), then convert
    float4 xv0[4][2], xv1[4][2];
#pragma unroll
    for (int mt = 0; mt < 4; ++mt)
#pragma unroll
        for (int kb = 0; kb < 2; ++kb) {
            const float* gp = x + (((size_t)(c * 64 + mt * 16 + lm)) * 64 + bb) * 64 + kb * 32 + lg * 8;
            xv0[mt][kb] = *(const float4*)gp;
            xv1[mt][kb] = *(const float4*)(gp + 4);
        }
    U8 xf[4][2];
#pragma unroll
    for (int mt = 0; mt < 4; ++mt)
#pragma unroll
        for (int kb = 0; kb < 2; ++kb)
            rne8(xv0[mt][kb], xv1[mt][kb], xf[mt][kb]);

    f32x4 acc[4][4];
#pragma unroll
    for (int mt = 0; mt < 4; ++mt)
#pragma unroll
        for (int nt = 0; nt < 4; ++nt) acc[mt][nt] = (f32x4){0.f, 0.f, 0.f, 0.f};

#pragma unroll
    for (int ntl = 0; ntl < 4; ++ntl)
#pragma unroll
        for (int kb = 0; kb < 2; ++kb)
#pragma unroll
            for (int mt = 0; mt < 4; ++mt)
                acc[mt][ntl] = __builtin_amdgcn_mfma_f32_16x16x32_bf16(xf[mt][kb].v, bf[kb][ntl], acc[mt][ntl], 0, 0, 0);

    // in-register weighted reduction to r_c
#pragma unroll
    for (int ntl = 0; ntl < 4; ++ntl) {
        const int hid = (w * 4 + ntl) * 16 + lm;
        const float ah  = a[hid];
        const float a2  = ah * ah;
        const float a4  = a2 * a2;
        const float a8  = a4 * a4;
        const float a16 = a8 * a8;
        const float w3  = a8 * a4;                       // a^12
        const float inva4 = __builtin_amdgcn_rcpf(a4);
        const float inva8 = inva4 * inva4;
        const float tinv  = ((lg & 1) ? inva4 : 1.0f) * ((lg & 2) ? inva8 : 1.0f);

        float S = 0.f;
#pragma unroll
        for (int mt = 0; mt < 4; ++mt) {
            const f32x4 p = acc[mt][ntl];
            // R = a^3*xb0 + a^2*xb1 + a*xb2 + xb3
            float R = fmaf(fmaf(fmaf(p[0], ah, p[1]), ah, p[2]), ah, p[3]);
            float Rp = R * tinv;                          // pre-scale by a4^-lg
            Rp += __shfl_xor(Rp, 16);
            Rp += __shfl_xor(Rp, 32);
            S = fmaf(a16, S, w3 * Rp);                    // S = a^16 S + a^12 * sum
        }
        if (lg == 0) r[((size_t)c * B_ + bb) * DH_ + hid] = S;
    }
}

// ---------------------------------------------------------------------------
// k_scan: sequential scan over chunk aggregates, IN PLACE (r becomes Hst).
// All 64 r-loads preloaded into registers (no serial load latency).
// ---------------------------------------------------------------------------
__global__ __launch_bounds__(512) void k_scan(
    const float* __restrict__ h0, const float* __restrict__ a,
    float* __restrict__ r, float* __restrict__ hfin)
{
    const int bb  = blockIdx.x;
    const int hid = threadIdx.x;
    const size_t base = (size_t)bb * DH_ + hid;

    float rv[C_];
#pragma unroll
    for (int c = 0; c < C_; ++c) rv[c] = r[(size_t)c * B_ * DH_ + base];

    float h  = h0[base];
    float aL = a[hid];
#pragma unroll
    for (int q = 0; q < 6; ++q) aL = aL * aL;   // a^64

#pragma unroll
    for (int c = 0; c < C_; ++c) {
        r[(size_t)c * B_ * DH_ + base] = h;      // Hst[c] = state BEFORE chunk c
        h = fmaf(h, aL, rv[c]);
    }
    hfin[base] = h;
}

// ---------------------------------------------------------------------------
// k_y: per (chunk, batch) block, 512 threads, LDS 68 KB -> 2 blocks/CU.
//  ph2: xb = x @ b, 1-term bf16 MFMA, all global loads hoisted; pack acc
//       (4 consec s) as u32 bf16-pairs, b64 write to LDS [hid][s].
//  ph3: wave-local xb read (no barrier), barrier, serial scan, bf16 h overlay.
//  ph4: y = h @ c single-term MFMA from swizzled LDS + c-frags.
// ---------------------------------------------------------------------------
__global__ __launch_bounds__(512, 4) void k_y(
    const float* __restrict__ x, const float* __restrict__ a,
    const unsigned short* __restrict__ bhi, const unsigned short* __restrict__ cfr,
    const float* __restrict__ Hst, float* __restrict__ y)
{
    extern __shared__ unsigned lds[];               // 512*34*4 = 69632 B
    unsigned short* hb = (unsigned short*)lds;      // overlay: [64 s][512 hid^swz]

    const int c    = blockIdx.x;
    const int bb   = blockIdx.y;
    const int tid  = threadIdx.x;
    const int lane = tid & 63;
    const int w    = tid >> 6;
    const int lm   = lane & 15;
    const int lg   = lane >> 4;

    // ---- ph2: xb = x @ b (1-term, hoisted loads) ----
    {
        bf16x8 bf[2][4];
#pragma unroll
        for (int kb = 0; kb < 2; ++kb)
#pragma unroll
            for (int ntl = 0; ntl < 4; ++ntl)
                bf[kb][ntl] = *(const bf16x8*)(bhi + ((size_t)(kb * 32 + w * 4 + ntl) * 64 + lane) * 8);

        float4 xv0[4][2], xv1[4][2];
#pragma unroll
        for (int mt = 0; mt < 4; ++mt)
#pragma unroll
            for (int kb = 0; kb < 2; ++kb) {
                const float* gp = x + (((size_t)(c * 64 + mt * 16 + lm)) * 64 + bb) * 64 + kb * 32 + lg * 8;
                xv0[mt][kb] = *(const float4*)gp;
                xv1[mt][kb] = *(const float4*)(gp + 4);
            }
        U8 xf[4][2];
#pragma unroll
        for (int mt = 0; mt < 4; ++mt)
#pragma unroll
            for (int kb = 0; kb < 2; ++kb)
                rne8(xv0[mt][kb], xv1[mt][kb], xf[mt][kb]);

        f32x4 acc[4][4];
#pragma unroll
        for (int mt = 0; mt < 4; ++mt)
#pragma unroll
            for (int nt = 0; nt < 4; ++nt) acc[mt][nt] = (f32x4){0.f, 0.f, 0.f, 0.f};

#pragma unroll
        for (int ntl = 0; ntl < 4; ++ntl)
#pragma unroll
            for (int kb = 0; kb < 2; ++kb)
#pragma unroll
                for (int mt = 0; mt < 4; ++mt)
                    acc[mt][ntl] = __builtin_amdgcn_mfma_f32_16x16x32_bf16(xf[mt][kb].v, bf[kb][ntl], acc[mt][ntl], 0, 0, 0);

        // pack 4 consecutive s (rg 0..3 at s0 = mt*16+lg*4) into 2 u32, b64 write
#pragma unroll
        for (int mt = 0; mt < 4; ++mt)
#pragma unroll
            for (int ntl = 0; ntl < 4; ++ntl) {
                const int hid = (w * 4 + ntl) * 16 + lm;
                const unsigned p0 = (unsigned)f2b_rne(acc[mt][ntl][0]) | ((unsigned)f2b_rne(acc[mt][ntl][1]) << 16);
                const unsigned p1 = (unsigned)f2b_rne(acc[mt][ntl][2]) | ((unsigned)f2b_rne(acc[mt][ntl][3]) << 16);
                uint2* dst = (uint2*)(lds + (size_t)hid * XBSTR + mt * 8 + lg * 2);
                *dst = make_uint2(p0, p1);
            }
    }
    // NO barrier: ph3 reads only this wave's own rows; lgkmcnt ordering suffices.

    // ---- ph3: per-hid serial scan ----
    {
        const int hid = tid;
        uint2 xr[16];
        const unsigned* rowp = lds + (size_t)hid * XBSTR;
#pragma unroll
        for (int j = 0; j < 16; ++j) xr[j] = *(const uint2*)(rowp + 2 * j);

        __syncthreads();   // all xb reads done before h overlay writes

        const float ah = a[hid];
        float h = Hst[((size_t)c * B_ + bb) * DH_ + hid];

#define STEP(xbits, sidx)                                                      \
        {                                                                      \
            h = fmaf(h, ah, __uint_as_float(xbits));                           \
            hb[(sidx) * DH_ + (hid ^ (((sidx) & 7) << 3))] = f2b_rne(h);       \
        }
#pragma unroll
        for (int j = 0; j < 16; ++j) {
            const unsigned ux = xr[j].x, uy = xr[j].y;
            STEP(ux << 16,          j * 4 + 0)
            STEP(ux & 0xffff0000u,  j * 4 + 1)
            STEP(uy << 16,          j * 4 + 2)
            STEP(uy & 0xffff0000u,  j * 4 + 3)
        }
#undef STEP
    }
    __syncthreads();

    // ---- ph4: y = h @ c (single-term bf16 MFMA) ----
    {
        const int mt  = w >> 1;
        const int oh  = w & 1;
        const int row = mt * 16 + lm;
        const int sw  = (row & 7) << 3;
        const unsigned short* hrow = hb + row * DH_;

        f32x4 acc0 = {0.f, 0.f, 0.f, 0.f};
        f32x4 acc1 = {0.f, 0.f, 0.f, 0.f};

#pragma unroll
        for (int kb = 0; kb < 16; ++kb) {
            const int k0 = kb * 32 + lg * 8;
            const bf16x8 af = *(const bf16x8*)(hrow + (k0 ^ sw));
            const bf16x8 c0 = *(const bf16x8*)(cfr + ((size_t)(kb * 4 + oh * 2 + 0) * 64 + lane) * 8);
            const bf16x8 c1 = *(const bf16x8*)(cfr + ((size_t)(kb * 4 + oh * 2 + 1) * 64 + lane) * 8);
            acc0 = __builtin_amdgcn_mfma_f32_16x16x32_bf16(af, c0, acc0, 0, 0, 0);
            acc1 = __builtin_amdgcn_mfma_f32_16x16x32_bf16(af, c1, acc1, 0, 0, 0);
        }

        // D layout: col = lane&15 (o), row = (lane>>4)*4 + reg (s)
#pragma unroll
        for (int rg = 0; rg < 4; ++rg) {
            const int sr = mt * 16 + lg * 4 + rg;
            float* yp = y + (((size_t)(c * 64 + sr)) * 64 + bb) * 64 + oh * 32 + lm;
            yp[0]  = acc0[rg];
            yp[16] = acc1[rg];
        }
    }
}

// ---------------------------------------------------------------------------
extern "C" void kernel_launch(void* const* d_in, const int* in_sizes, int n_in,
                              void* d_out, int out_size, void* d_ws, size_t ws_size,
                              hipStream_t stream) {
    (void)in_sizes; (void)n_in; (void)out_size; (void)ws_size;

    const float* h0 = (const float*)d_in[0];   // [B, DH]
    const float* x  = (const float*)d_in[1];   // [T, B, DI]
    const float* a  = (const float*)d_in[2];   // [DH]
    const float* bm = (const float*)d_in[3];   // [DI, DH]
    const float* cm = (const float*)d_in[4];   // [DH, DO]

    float* out  = (float*)d_out;
    float* hfin = out;                         // [B, DH]
    float* y    = out + (size_t)B_ * DH_;      // [T, B, DO]

    float* r = (float*)d_ws;                   // [C, B, DH] (8 MB) — becomes Hst in-place
    unsigned short* bhi = (unsigned short*)(r + (size_t)C_ * B_ * DH_);
    unsigned short* blo = bhi + 32768;
    unsigned short* cfr = blo + 32768;

    const size_t LDSZ_Y = (size_t)DH_ * XBSTR * 4;   // 69632 B

    k_frags<<<dim3(128), 256, 0, stream>>>(bm, cm, bhi, blo, cfr);
    k_r<<<dim3(C_, B_), 512, 0, stream>>>(x, a, bhi, r);
    k_scan<<<dim3(B_), 512, 0, stream>>>(h0, a, r, hfin);
    k_y<<<dim3(C_, B_), 512, LDSZ_Y, stream>>>(x, a, bhi, cfr, r, y);
}

// Round 7
// 144.358 us; speedup vs baseline: 11.5906x; 1.3576x over previous
//
#include <hip/hip_runtime.h>
#include <stdint.h>

// Problem constants
#define T_  4096
#define B_  64
#define DI_ 64
#define DH_ 512
#define DO_ 64
#define L_  64          // chunk length
#define C_  (T_ / L_)   // 64 chunks

// k_y LDS: xb region 512 rows x 34 dwords (136 B; 64 bf16 + 8 B pad)
#define XBSTR 34

typedef __attribute__((ext_vector_type(8))) short bf16x8;
typedef __attribute__((ext_vector_type(4))) float f32x4;

union U8 { uint4 q; bf16x8 v; };

__device__ inline unsigned short f2b_rne(float f) {
    unsigned u = __float_as_uint(f);
    return (unsigned short)((u + 0x7fffu + ((u >> 16) & 1u)) >> 16);
}

// rne-convert 8 f32 -> bf16x8
__device__ inline void rne8(const float4 v0, const float4 v1, U8& out) {
    const unsigned r0 = f2b_rne(v0.x), r1 = f2b_rne(v0.y),
                   r2 = f2b_rne(v0.z), r3 = f2b_rne(v0.w),
                   r4 = f2b_rne(v1.x), r5 = f2b_rne(v1.y),
                   r6 = f2b_rne(v1.z), r7 = f2b_rne(v1.w);
    out.q.x = r0 | (r1 << 16);
    out.q.y = r2 | (r3 << 16);
    out.q.z = r4 | (r5 << 16);
    out.q.w = r6 | (r7 << 16);
}

// ---------------------------------------------------------------------------
// k_frags: b -> bhi (bf16 frags) + u-weighted moment frags be1 = u*b,
// be2 = (u^2/2)*b  (u = ln a, per output col h); c -> cfr frags.
// Frag layout (all): [kb][nt][lane(g*16+n)][j]; element (i = kb*32+g*8+j,
// col = nt*16+n). grid 128 x 256.
// ---------------------------------------------------------------------------
__global__ __launch_bounds__(256) void k_frags(
    const float* __restrict__ bmat, const float* __restrict__ cmat,
    const float* __restrict__ a,
    unsigned short* __restrict__ bhi, unsigned short* __restrict__ be1,
    unsigned short* __restrict__ be2, unsigned short* __restrict__ cfr)
{
    const int t = blockIdx.x * 256 + threadIdx.x;   // 0..32767
    {
        const int j = t & 7, n = (t >> 3) & 15, g = (t >> 7) & 3;
        const int nt = (t >> 9) & 31, kb = (t >> 14) & 1;
        const int h = nt * 16 + n;
        const float v = bmat[(size_t)(kb * 32 + g * 8 + j) * DH_ + h];
        const float u = logf(a[h]);
        bhi[t] = f2b_rne(v);
        be1[t] = f2b_rne(v * u);
        be2[t] = f2b_rne(v * u * u * 0.5f);
    }
    {
        const int j = t & 7, n = (t >> 3) & 15, g = (t >> 7) & 3;
        const int nt = (t >> 9) & 3, kb = (t >> 11) & 15;
        float v = cmat[(size_t)(kb * 32 + g * 8 + j) * DO_ + nt * 16 + n];
        cfr[t] = f2b_rne(v);
    }
}

// ---------------------------------------------------------------------------
// k_mom: per-chunk moment reduction over x (pure streaming, memory-bound).
// X_k[c][k][bb*64+i] = sum_s (63-s)^k * x[c*64+s][bb][i], k = 0,1,2 (bf16).
// grid (C_, 16) x 256 threads; coalesced 1024B/wave loads.
// ---------------------------------------------------------------------------
__global__ __launch_bounds__(256) void k_mom(
    const float* __restrict__ x, unsigned short* __restrict__ Xm)
{
    const int c   = blockIdx.x;
    const int idx = blockIdx.y * 256 + threadIdx.x;   // (bb*64 + i), 0..4095
    const float* xp = x + (size_t)c * 64 * 4096 + idx;

    float m0 = 0.f, m1 = 0.f, m2 = 0.f;
#pragma unroll
    for (int s = 0; s < 64; ++s) {
        const float v = xp[(size_t)s * 4096];
        const float t = (float)(63 - s);
        m0 += v;
        m1 = fmaf(t, v, m1);
        m2 = fmaf(t * t, v, m2);
    }
    Xm[(size_t)(c * 3 + 0) * 4096 + idx] = f2b_rne(m0);
    Xm[(size_t)(c * 3 + 1) * 4096 + idx] = f2b_rne(m1);
    Xm[(size_t)(c * 3 + 2) * 4096 + idx] = f2b_rne(m2);
}

// ---------------------------------------------------------------------------
// k_rg: r[c][bb][h] = sum_k (u^k/k!)(X_k @ b)[h] as ONE GEMM: A = [X0|X1|X2]
// ([64 bb] x [192 k]), B = [b; u*b; u^2/2*b] (pre-folded frags). M=64, N=512,
// K=192. grid (C_, 2 n-halves) x 512 thr; wave w: 4 m-tiles x 2 n-tiles, all
// frags hoisted (36 loads in flight).
// ---------------------------------------------------------------------------
__global__ __launch_bounds__(512) void k_rg(
    const unsigned short* __restrict__ Xm,
    const unsigned short* __restrict__ bhi, const unsigned short* __restrict__ be1,
    const unsigned short* __restrict__ be2,
    float* __restrict__ r)
{
    const int c    = blockIdx.x;
    const int nh   = blockIdx.y;
    const int tid  = threadIdx.x;
    const int lane = tid & 63;
    const int w    = tid >> 6;
    const int lm   = lane & 15;
    const int lg   = lane >> 4;

    bf16x8 af[4][6];
#pragma unroll
    for (int mt = 0; mt < 4; ++mt)
#pragma unroll
        for (int kb = 0; kb < 6; ++kb) {
            const int mom = kb >> 1;
            af[mt][kb] = *(const bf16x8*)(Xm + (size_t)(c * 3 + mom) * 4096
                                          + (mt * 16 + lm) * 64 + (kb & 1) * 32 + lg * 8);
        }

    bf16x8 bfr[6][2];
#pragma unroll
    for (int kb = 0; kb < 6; ++kb) {
        const int mom = kb >> 1;
        const unsigned short* base = (mom == 0) ? bhi : (mom == 1) ? be1 : be2;
#pragma unroll
        for (int nt = 0; nt < 2; ++nt) {
            const int ntg = nh * 16 + w * 2 + nt;
            bfr[kb][nt] = *(const bf16x8*)(base + ((size_t)((kb & 1) * 32 + ntg) * 64 + lane) * 8);
        }
    }

    f32x4 acc[4][2];
#pragma unroll
    for (int mt = 0; mt < 4; ++mt)
#pragma unroll
        for (int nt = 0; nt < 2; ++nt) acc[mt][nt] = (f32x4){0.f, 0.f, 0.f, 0.f};

#pragma unroll
    for (int kb = 0; kb < 6; ++kb)
#pragma unroll
        for (int nt = 0; nt < 2; ++nt)
#pragma unroll
            for (int mt = 0; mt < 4; ++mt)
                acc[mt][nt] = __builtin_amdgcn_mfma_f32_16x16x32_bf16(af[mt][kb], bfr[kb][nt], acc[mt][nt], 0, 0, 0);

    // D: col = lm (h within ntile), row = lg*4+rg (bb within mtile)
#pragma unroll
    for (int mt = 0; mt < 4; ++mt)
#pragma unroll
        for (int nt = 0; nt < 2; ++nt)
#pragma unroll
            for (int rg = 0; rg < 4; ++rg) {
                const int bb = mt * 16 + lg * 4 + rg;
                const int h  = nh * 256 + w * 32 + nt * 16 + lm;
                r[((size_t)c * B_ + bb) * DH_ + h] = acc[mt][nt][rg];
            }
}

// ---------------------------------------------------------------------------
// k_scan: sequential scan over chunk aggregates, IN PLACE (r becomes Hst).
// ---------------------------------------------------------------------------
__global__ __launch_bounds__(512) void k_scan(
    const float* __restrict__ h0, const float* __restrict__ a,
    float* __restrict__ r, float* __restrict__ hfin)
{
    const int bb  = blockIdx.x;
    const int hid = threadIdx.x;
    const size_t base = (size_t)bb * DH_ + hid;

    float rv[C_];
#pragma unroll
    for (int c = 0; c < C_; ++c) rv[c] = r[(size_t)c * B_ * DH_ + base];

    float h  = h0[base];
    float aL = a[hid];
#pragma unroll
    for (int q = 0; q < 6; ++q) aL = aL * aL;   // a^64

#pragma unroll
    for (int c = 0; c < C_; ++c) {
        r[(size_t)c * B_ * DH_ + base] = h;      // Hst[c] = state BEFORE chunk c
        h = fmaf(h, aL, rv[c]);
    }
    hfin[base] = h;
}

// ---------------------------------------------------------------------------
// k_y: per (chunk, batch) block, 512 threads, LDS 68 KB -> 2 blocks/CU.
//  ph2: xb = x @ b, 1-term bf16 MFMA, hoisted loads; pack to LDS [hid][s].
//  ph3: wave-local xb read (no barrier), barrier, serial scan, bf16 h overlay.
//  ph4: y = h @ c, cfr frags group-hoisted (rolling 2x4kb double-buffer so
//       >=8 loads stay in flight ahead of the MFMAs).
// ---------------------------------------------------------------------------
__global__ __launch_bounds__(512, 4) void k_y(
    const float* __restrict__ x, const float* __restrict__ a,
    const unsigned short* __restrict__ bhi, const unsigned short* __restrict__ cfr,
    const float* __restrict__ Hst, float* __restrict__ y)
{
    extern __shared__ unsigned lds[];               // 512*34*4 = 69632 B
    unsigned short* hb = (unsigned short*)lds;      // overlay: [64 s][512 hid^swz]

    const int c    = blockIdx.x;
    const int bb   = blockIdx.y;
    const int tid  = threadIdx.x;
    const int lane = tid & 63;
    const int w    = tid >> 6;
    const int lm   = lane & 15;
    const int lg   = lane >> 4;

    // early Hst prefetch (consumed in ph3)
    const float hstart = Hst[((size_t)c * B_ + bb) * DH_ + tid];

    // ---- ph2: xb = x @ b (1-term, hoisted loads) ----
    {
        bf16x8 bf[2][4];
#pragma unroll
        for (int kb = 0; kb < 2; ++kb)
#pragma unroll
            for (int ntl = 0; ntl < 4; ++ntl)
                bf[kb][ntl] = *(const bf16x8*)(bhi + ((size_t)(kb * 32 + w * 4 + ntl) * 64 + lane) * 8);

        float4 xv0[4][2], xv1[4][2];
#pragma unroll
        for (int mt = 0; mt < 4; ++mt)
#pragma unroll
            for (int kb = 0; kb < 2; ++kb) {
                const float* gp = x + (((size_t)(c * 64 + mt * 16 + lm)) * 64 + bb) * 64 + kb * 32 + lg * 8;
                xv0[mt][kb] = *(const float4*)gp;
                xv1[mt][kb] = *(const float4*)(gp + 4);
            }
        U8 xf[4][2];
#pragma unroll
        for (int mt = 0; mt < 4; ++mt)
#pragma unroll
            for (int kb = 0; kb < 2; ++kb)
                rne8(xv0[mt][kb], xv1[mt][kb], xf[mt][kb]);

        f32x4 acc[4][4];
#pragma unroll
        for (int mt = 0; mt < 4; ++mt)
#pragma unroll
            for (int nt = 0; nt < 4; ++nt) acc[mt][nt] = (f32x4){0.f, 0.f, 0.f, 0.f};

#pragma unroll
        for (int ntl = 0; ntl < 4; ++ntl)
#pragma unroll
            for (int kb = 0; kb < 2; ++kb)
#pragma unroll
                for (int mt = 0; mt < 4; ++mt)
                    acc[mt][ntl] = __builtin_amdgcn_mfma_f32_16x16x32_bf16(xf[mt][kb].v, bf[kb][ntl], acc[mt][ntl], 0, 0, 0);

        // pack 4 consecutive s (rg 0..3 at s0 = mt*16+lg*4) into 2 u32, b64 write
#pragma unroll
        for (int mt = 0; mt < 4; ++mt)
#pragma unroll
            for (int ntl = 0; ntl < 4; ++ntl) {
                const int hid = (w * 4 + ntl) * 16 + lm;
                const unsigned p0 = (unsigned)f2b_rne(acc[mt][ntl][0]) | ((unsigned)f2b_rne(acc[mt][ntl][1]) << 16);
                const unsigned p1 = (unsigned)f2b_rne(acc[mt][ntl][2]) | ((unsigned)f2b_rne(acc[mt][ntl][3]) << 16);
                uint2* dst = (uint2*)(lds + (size_t)hid * XBSTR + mt * 8 + lg * 2);
                *dst = make_uint2(p0, p1);
            }
    }
    // NO barrier: ph3 reads only this wave's own rows; lgkmcnt ordering suffices.

    // ---- ph3: per-hid serial scan ----
    {
        const int hid = tid;
        uint2 xr[16];
        const unsigned* rowp = lds + (size_t)hid * XBSTR;
#pragma unroll
        for (int j = 0; j < 16; ++j) xr[j] = *(const uint2*)(rowp + 2 * j);

        __syncthreads();   // all xb reads done before h overlay writes

        const float ah = a[hid];
        float h = hstart;

#define STEP(xbits, sidx)                                                      \
        {                                                                      \
            h = fmaf(h, ah, __uint_as_float(xbits));                           \
            hb[(sidx) * DH_ + (hid ^ (((sidx) & 7) << 3))] = f2b_rne(h);       \
        }
#pragma unroll
        for (int j = 0; j < 16; ++j) {
            const unsigned ux = xr[j].x, uy = xr[j].y;
            STEP(ux << 16,          j * 4 + 0)
            STEP(ux & 0xffff0000u,  j * 4 + 1)
            STEP(uy << 16,          j * 4 + 2)
            STEP(uy & 0xffff0000u,  j * 4 + 3)
        }
#undef STEP
    }
    __syncthreads();

    // ---- ph4: y = h @ c (rolling group-hoisted cfr frags) ----
    {
        const int mt  = w >> 1;
        const int oh  = w & 1;
        const int row = mt * 16 + lm;
        const int sw  = (row & 7) << 3;
        const unsigned short* hrow = hb + row * DH_;

        f32x4 acc0 = {0.f, 0.f, 0.f, 0.f};
        f32x4 acc1 = {0.f, 0.f, 0.f, 0.f};

#define LDC(kb, n2) (*(const bf16x8*)(cfr + (size_t)((kb) * 4 + oh * 2 + (n2)) * 512 + lane * 8))
#define LDA(kb)     (*(const bf16x8*)(hrow + (((kb) * 32 + lg * 8) ^ sw)))

        bf16x8 cA[4][2], cB[4][2];
#pragma unroll
        for (int k = 0; k < 4; ++k) { cA[k][0] = LDC(k, 0);      cA[k][1] = LDC(k, 1); }
#pragma unroll
        for (int k = 0; k < 4; ++k) { cB[k][0] = LDC(4 + k, 0);  cB[k][1] = LDC(4 + k, 1); }
#pragma unroll
        for (int k = 0; k < 4; ++k) {
            const bf16x8 af = LDA(k);
            acc0 = __builtin_amdgcn_mfma_f32_16x16x32_bf16(af, cA[k][0], acc0, 0, 0, 0);
            acc1 = __builtin_amdgcn_mfma_f32_16x16x32_bf16(af, cA[k][1], acc1, 0, 0, 0);
        }
#pragma unroll
        for (int k = 0; k < 4; ++k) { cA[k][0] = LDC(8 + k, 0);  cA[k][1] = LDC(8 + k, 1); }
#pragma unroll
        for (int k = 0; k < 4; ++k) {
            const bf16x8 af = LDA(4 + k);
            acc0 = __builtin_amdgcn_mfma_f32_16x16x32_bf16(af, cB[k][0], acc0, 0, 0, 0);
            acc1 = __builtin_amdgcn_mfma_f32_16x16x32_bf16(af, cB[k][1], acc1, 0, 0, 0);
        }
#pragma unroll
        for (int k = 0; k < 4; ++k) { cB[k][0] = LDC(12 + k, 0); cB[k][1] = LDC(12 + k, 1); }
#pragma unroll
        for (int k = 0; k < 4; ++k) {
            const bf16x8 af = LDA(8 + k);
            acc0 = __builtin_amdgcn_mfma_f32_16x16x32_bf16(af, cA[k][0], acc0, 0, 0, 0);
            acc1 = __builtin_amdgcn_mfma_f32_16x16x32_bf16(af, cA[k][1], acc1, 0, 0, 0);
        }
#pragma unroll
        for (int k = 0; k < 4; ++k) {
            const bf16x8 af = LDA(12 + k);
            acc0 = __builtin_amdgcn_mfma_f32_16x16x32_bf16(af, cB[k][0], acc0, 0, 0, 0);
            acc1 = __builtin_amdgcn_mfma_f32_16x16x32_bf16(af, cB[k][1], acc1, 0, 0, 0);
        }
#undef LDC
#undef LDA

        // D layout: col = lane&15 (o), row = (lane>>4)*4 + reg (s)
#pragma unroll
        for (int rg = 0; rg < 4; ++rg) {
            const int sr = mt * 16 + lg * 4 + rg;
            float* yp = y + (((size_t)(c * 64 + sr)) * 64 + bb) * 64 + oh * 32 + lm;
            yp[0]  = acc0[rg];
            yp[16] = acc1[rg];
        }
    }
}

// ---------------------------------------------------------------------------
extern "C" void kernel_launch(void* const* d_in, const int* in_sizes, int n_in,
                              void* d_out, int out_size, void* d_ws, size_t ws_size,
                              hipStream_t stream) {
    (void)in_sizes; (void)n_in; (void)out_size; (void)ws_size;

    const float* h0 = (const float*)d_in[0];   // [B, DH]
    const float* x  = (const float*)d_in[1];   // [T, B, DI]
    const float* a  = (const float*)d_in[2];   // [DH]
    const float* bm = (const float*)d_in[3];   // [DI, DH]
    const float* cm = (const float*)d_in[4];   // [DH, DO]

    float* out  = (float*)d_out;
    float* hfin = out;                         // [B, DH]
    float* y    = out + (size_t)B_ * DH_;      // [T, B, DO]

    float* r = (float*)d_ws;                   // [C, B, DH] (8 MB) — becomes Hst in-place
    unsigned short* bhi = (unsigned short*)(r + (size_t)C_ * B_ * DH_);
    unsigned short* be1 = bhi + 32768;
    unsigned short* be2 = be1 + 32768;
    unsigned short* cfr = be2 + 32768;
    unsigned short* Xm  = cfr + 32768;         // [C][3][4096] bf16 (1.5 MB)

    const size_t LDSZ_Y = (size_t)DH_ * XBSTR * 4;   // 69632 B

    k_frags<<<dim3(128), 256, 0, stream>>>(bm, cm, a, bhi, be1, be2, cfr);
    k_mom<<<dim3(C_, 16), 256, 0, stream>>>(x, Xm);
    k_rg<<<dim3(C_, 2), 512, 0, stream>>>(Xm, bhi, be1, be2, r);
    k_scan<<<dim3(B_), 512, 0, stream>>>(h0, a, r, hfin);
    k_y<<<dim3(C_, B_), 512, LDSZ_Y, stream>>>(x, a, bhi, cfr, r, y);
}

// Round 9
// 135.494 us; speedup vs baseline: 12.3488x; 1.0654x over previous
//
#include <hip/hip_runtime.h>
#include <stdint.h>

// Problem constants
#define T_  4096
#define B_  64
#define DI_ 64
#define DH_ 512
#define DO_ 64
#define L_  64          // chunk length
#define C_  (T_ / L_)   // 64 chunks

// k_y LDS: xb region 512 rows x 34 dwords (136 B; 64 bf16 + 8 B pad)
#define XBSTR 34

typedef __attribute__((ext_vector_type(8))) short bf16x8;
typedef __attribute__((ext_vector_type(4))) float f32x4;

union U8 { uint4 q; bf16x8 v; };

__device__ inline unsigned short f2b_rne(float f) {
    unsigned u = __float_as_uint(f);
    return (unsigned short)((u + 0x7fffu + ((u >> 16) & 1u)) >> 16);
}

// rne-convert 8 f32 -> bf16x8 (proven-good scalar path)
__device__ inline void rne8(const float4 v0, const float4 v1, U8& out) {
    const unsigned r0 = f2b_rne(v0.x), r1 = f2b_rne(v0.y),
                   r2 = f2b_rne(v0.z), r3 = f2b_rne(v0.w),
                   r4 = f2b_rne(v1.x), r5 = f2b_rne(v1.y),
                   r6 = f2b_rne(v1.z), r7 = f2b_rne(v1.w);
    out.q.x = r0 | (r1 << 16);
    out.q.y = r2 | (r3 << 16);
    out.q.z = r4 | (r5 << 16);
    out.q.w = r6 | (r7 << 16);
}

// ---------------------------------------------------------------------------
// k_frags: b -> bhi frags + u-weighted moment frags be1 = u*b, be2 = (u^2/2)*b
// (u = ln a per col h); c -> cfr frags. Layout: [kb][nt][lane][8].
// ---------------------------------------------------------------------------
__global__ __launch_bounds__(256) void k_frags(
    const float* __restrict__ bmat, const float* __restrict__ cmat,
    const float* __restrict__ a,
    unsigned short* __restrict__ bhi, unsigned short* __restrict__ be1,
    unsigned short* __restrict__ be2, unsigned short* __restrict__ cfr)
{
    const int t = blockIdx.x * 256 + threadIdx.x;   // 0..32767
    {
        const int j = t & 7, n = (t >> 3) & 15, g = (t >> 7) & 3;
        const int nt = (t >> 9) & 31, kb = (t >> 14) & 1;
        const int h = nt * 16 + n;
        const float v = bmat[(size_t)(kb * 32 + g * 8 + j) * DH_ + h];
        const float u = logf(a[h]);
        bhi[t] = f2b_rne(v);
        be1[t] = f2b_rne(v * u);
        be2[t] = f2b_rne(v * u * u * 0.5f);
    }
    {
        const int j = t & 7, n = (t >> 3) & 15, g = (t >> 7) & 3;
        const int nt = (t >> 9) & 3, kb = (t >> 11) & 15;
        float v = cmat[(size_t)(kb * 32 + g * 8 + j) * DO_ + nt * 16 + n];
        cfr[t] = f2b_rne(v);
    }
}

// ---------------------------------------------------------------------------
// k_mom: per-chunk moment reduction over x (streaming, memory-bound).
// X_k[c][k][bb*64+i] = sum_s (63-s)^k * x[c*64+s][bb][i], k = 0,1,2 (bf16).
// ---------------------------------------------------------------------------
__global__ __launch_bounds__(256) void k_mom(
    const float* __restrict__ x, unsigned short* __restrict__ Xm)
{
    const int c   = blockIdx.x;
    const int idx = blockIdx.y * 256 + threadIdx.x;   // (bb*64 + i)
    const float* xp = x + (size_t)c * 64 * 4096 + idx;

    float m0 = 0.f, m1 = 0.f, m2 = 0.f;
#pragma unroll
    for (int s = 0; s < 64; ++s) {
        const float v = xp[(size_t)s * 4096];
        const float t = (float)(63 - s);
        m0 += v;
        m1 = fmaf(t, v, m1);
        m2 = fmaf(t * t, v, m2);
    }
    Xm[(size_t)(c * 3 + 0) * 4096 + idx] = f2b_rne(m0);
    Xm[(size_t)(c * 3 + 1) * 4096 + idx] = f2b_rne(m1);
    Xm[(size_t)(c * 3 + 2) * 4096 + idx] = f2b_rne(m2);
}

// ---------------------------------------------------------------------------
// k_rg: r[c][bb][h] = sum_k (u^k/k!)(X_k @ b)[h] as one GEMM, K=192 folded.
// ---------------------------------------------------------------------------
__global__ __launch_bounds__(512) void k_rg(
    const unsigned short* __restrict__ Xm,
    const unsigned short* __restrict__ bhi, const unsigned short* __restrict__ be1,
    const unsigned short* __restrict__ be2,
    float* __restrict__ r)
{
    const int c    = blockIdx.x;
    const int nh   = blockIdx.y;
    const int tid  = threadIdx.x;
    const int lane = tid & 63;
    const int w    = tid >> 6;
    const int lm   = lane & 15;
    const int lg   = lane >> 4;

    bf16x8 af[4][6];
#pragma unroll
    for (int mt = 0; mt < 4; ++mt)
#pragma unroll
        for (int kb = 0; kb < 6; ++kb) {
            const int mom = kb >> 1;
            af[mt][kb] = *(const bf16x8*)(Xm + (size_t)(c * 3 + mom) * 4096
                                          + (mt * 16 + lm) * 64 + (kb & 1) * 32 + lg * 8);
        }

    bf16x8 bfr[6][2];
#pragma unroll
    for (int kb = 0; kb < 6; ++kb) {
        const int mom = kb >> 1;
        const unsigned short* base = (mom == 0) ? bhi : (mom == 1) ? be1 : be2;
#pragma unroll
        for (int nt = 0; nt < 2; ++nt) {
            const int ntg = nh * 16 + w * 2 + nt;
            bfr[kb][nt] = *(const bf16x8*)(base + ((size_t)((kb & 1) * 32 + ntg) * 64 + lane) * 8);
        }
    }

    f32x4 acc[4][2];
#pragma unroll
    for (int mt = 0; mt < 4; ++mt)
#pragma unroll
        for (int nt = 0; nt < 2; ++nt) acc[mt][nt] = (f32x4){0.f, 0.f, 0.f, 0.f};

#pragma unroll
    for (int kb = 0; kb < 6; ++kb)
#pragma unroll
        for (int nt = 0; nt < 2; ++nt)
#pragma unroll
            for (int mt = 0; mt < 4; ++mt)
                acc[mt][nt] = __builtin_amdgcn_mfma_f32_16x16x32_bf16(af[mt][kb], bfr[kb][nt], acc[mt][nt], 0, 0, 0);

#pragma unroll
    for (int mt = 0; mt < 4; ++mt)
#pragma unroll
        for (int nt = 0; nt < 2; ++nt)
#pragma unroll
            for (int rg = 0; rg < 4; ++rg) {
                const int bb = mt * 16 + lg * 4 + rg;
                const int h  = nh * 256 + w * 32 + nt * 16 + lm;
                r[((size_t)c * B_ + bb) * DH_ + h] = acc[mt][nt][rg];
            }
}

// ---------------------------------------------------------------------------
// k_scan: sequential scan over chunk aggregates, IN PLACE (r becomes Hst).
// ---------------------------------------------------------------------------
__global__ __launch_bounds__(512) void k_scan(
    const float* __restrict__ h0, const float* __restrict__ a,
    float* __restrict__ r, float* __restrict__ hfin)
{
    const int bb  = blockIdx.x;
    const int hid = threadIdx.x;
    const size_t base = (size_t)bb * DH_ + hid;

    float rv[C_];
#pragma unroll
    for (int c = 0; c < C_; ++c) rv[c] = r[(size_t)c * B_ * DH_ + base];

    float h  = h0[base];
    float aL = a[hid];
#pragma unroll
    for (int q = 0; q < 6; ++q) aL = aL * aL;   // a^64

#pragma unroll
    for (int c = 0; c < C_; ++c) {
        r[(size_t)c * B_ * DH_ + base] = h;      // Hst[c] = state BEFORE chunk c
        h = fmaf(h, aL, rv[c]);
    }
    hfin[base] = h;
}

// ---------------------------------------------------------------------------
// k_y: per (chunk, batch) block, 512 threads, LDS 68 KB -> 2 blocks/CU.
//  ph2: xb = x @ b (1-term bf16 MFMA, rne8 converts); pack to LDS [hid][s].
//  cfr preload: wave role (mp = w>>2 s-half, oq = w&3 o-quarter) -> 16 frags
//    per wave, issued BEFORE ph3's __syncthreads (full fence pins them;
//    latency hides under the serial scan chain).
//  ph3: wave-local xb read (no barrier), barrier, serial scan, f2b_rne store.
//  ph4: y = h @ c from register-resident cfr, setprio around MFMA cluster.
// ---------------------------------------------------------------------------
__global__ __launch_bounds__(512, 4) void k_y(
    const float* __restrict__ x, const float* __restrict__ a,
    const unsigned short* __restrict__ bhi, const unsigned short* __restrict__ cfr,
    const float* __restrict__ Hst, float* __restrict__ y)
{
    extern __shared__ unsigned lds[];               // 512*34*4 = 69632 B
    unsigned short* hb = (unsigned short*)lds;      // overlay: [64 s][512 hid^swz]

    const int c    = blockIdx.x;
    const int bb   = blockIdx.y;
    const int tid  = threadIdx.x;
    const int lane = tid & 63;
    const int w    = tid >> 6;
    const int lm   = lane & 15;
    const int lg   = lane >> 4;

    // early Hst prefetch (consumed in ph3)
    const float hstart = Hst[((size_t)c * B_ + bb) * DH_ + tid];

    // ---- ph2: xb = x @ b (1-term, hoisted loads) ----
    {
        bf16x8 bf[2][4];
#pragma unroll
        for (int kb = 0; kb < 2; ++kb)
#pragma unroll
            for (int ntl = 0; ntl < 4; ++ntl)
                bf[kb][ntl] = *(const bf16x8*)(bhi + ((size_t)(kb * 32 + w * 4 + ntl) * 64 + lane) * 8);

        float4 xv0[4][2], xv1[4][2];
#pragma unroll
        for (int mt = 0; mt < 4; ++mt)
#pragma unroll
            for (int kb = 0; kb < 2; ++kb) {
                const float* gp = x + (((size_t)(c * 64 + mt * 16 + lm)) * 64 + bb) * 64 + kb * 32 + lg * 8;
                xv0[mt][kb] = *(const float4*)gp;
                xv1[mt][kb] = *(const float4*)(gp + 4);
            }
        U8 xf[4][2];
#pragma unroll
        for (int mt = 0; mt < 4; ++mt)
#pragma unroll
            for (int kb = 0; kb < 2; ++kb)
                rne8(xv0[mt][kb], xv1[mt][kb], xf[mt][kb]);

        f32x4 acc[4][4];
#pragma unroll
        for (int mt = 0; mt < 4; ++mt)
#pragma unroll
            for (int nt = 0; nt < 4; ++nt) acc[mt][nt] = (f32x4){0.f, 0.f, 0.f, 0.f};

#pragma unroll
        for (int ntl = 0; ntl < 4; ++ntl)
#pragma unroll
            for (int kb = 0; kb < 2; ++kb)
#pragma unroll
                for (int mt = 0; mt < 4; ++mt)
                    acc[mt][ntl] = __builtin_amdgcn_mfma_f32_16x16x32_bf16(xf[mt][kb].v, bf[kb][ntl], acc[mt][ntl], 0, 0, 0);

        // pack 4 consecutive s (rg 0..3 at s0 = mt*16+lg*4) into 2 u32, b64 write
#pragma unroll
        for (int mt = 0; mt < 4; ++mt)
#pragma unroll
            for (int ntl = 0; ntl < 4; ++ntl) {
                const int hid = (w * 4 + ntl) * 16 + lm;
                const unsigned p0 = (unsigned)f2b_rne(acc[mt][ntl][0]) | ((unsigned)f2b_rne(acc[mt][ntl][1]) << 16);
                const unsigned p1 = (unsigned)f2b_rne(acc[mt][ntl][2]) | ((unsigned)f2b_rne(acc[mt][ntl][3]) << 16);
                uint2* dst = (uint2*)(lds + (size_t)hid * XBSTR + mt * 8 + lg * 2);
                *dst = make_uint2(p0, p1);
            }
    }
    // NO barrier: ph3 reads only this wave's own rows; lgkmcnt ordering suffices.

    // ---- cfr preload for ph4 (pinned before ph3's __syncthreads) ----
    // ph4 wave role: mp = w>>2 (s-half), oq = w&3 (o-quarter, 16 wide)
    const int mp = w >> 2;
    const int oq = w & 3;
    bf16x8 cpre[16];
#pragma unroll
    for (int kb = 0; kb < 16; ++kb)
        cpre[kb] = *(const bf16x8*)(cfr + ((size_t)(kb * 4 + oq) * 64 + lane) * 8);

    // ---- ph3: per-hid serial scan ----
    {
        const int hid = tid;
        uint2 xr[16];
        const unsigned* rowp = lds + (size_t)hid * XBSTR;
#pragma unroll
        for (int j = 0; j < 16; ++j) xr[j] = *(const uint2*)(rowp + 2 * j);

        __syncthreads();   // all xb reads done before h overlay writes

        const float ah = a[hid];
        float h = hstart;

#define STEP(xbits, sidx)                                                      \
        {                                                                      \
            h = fmaf(h, ah, __uint_as_float(xbits));                           \
            hb[(sidx) * DH_ + (hid ^ (((sidx) & 7) << 3))] = f2b_rne(h);       \
        }
#pragma unroll
        for (int j = 0; j < 16; ++j) {
            const unsigned ux = xr[j].x, uy = xr[j].y;
            STEP(ux << 16,          j * 4 + 0)
            STEP(ux & 0xffff0000u,  j * 4 + 1)
            STEP(uy << 16,          j * 4 + 2)
            STEP(uy & 0xffff0000u,  j * 4 + 3)
        }
#undef STEP
    }
    __syncthreads();

    // ---- ph4: y = h @ c (cfr in registers; 2 m-tiles x 1 o-quarter) ----
    {
        f32x4 acc0 = {0.f, 0.f, 0.f, 0.f};   // mt = mp*2
        f32x4 acc1 = {0.f, 0.f, 0.f, 0.f};   // mt = mp*2+1
        const int row0 = (mp * 2 + 0) * 16 + lm;
        const int row1 = (mp * 2 + 1) * 16 + lm;
        const int sw0 = (row0 & 7) << 3;
        const int sw1 = (row1 & 7) << 3;
        const unsigned short* hr0 = hb + row0 * DH_;
        const unsigned short* hr1 = hb + row1 * DH_;

        __builtin_amdgcn_s_setprio(1);
#pragma unroll
        for (int kb = 0; kb < 16; ++kb) {
            const int k0 = kb * 32 + lg * 8;
            const bf16x8 a0 = *(const bf16x8*)(hr0 + (k0 ^ sw0));
            const bf16x8 a1 = *(const bf16x8*)(hr1 + (k0 ^ sw1));
            acc0 = __builtin_amdgcn_mfma_f32_16x16x32_bf16(a0, cpre[kb], acc0, 0, 0, 0);
            acc1 = __builtin_amdgcn_mfma_f32_16x16x32_bf16(a1, cpre[kb], acc1, 0, 0, 0);
        }
        __builtin_amdgcn_s_setprio(0);

        // D layout: col = lm (o), row = lg*4 + rg (s within tile)
#pragma unroll
        for (int rg = 0; rg < 4; ++rg) {
            const int sr0 = (mp * 2 + 0) * 16 + lg * 4 + rg;
            const int sr1 = (mp * 2 + 1) * 16 + lg * 4 + rg;
            y[(((size_t)(c * 64 + sr0)) * 64 + bb) * 64 + oq * 16 + lm] = acc0[rg];
            y[(((size_t)(c * 64 + sr1)) * 64 + bb) * 64 + oq * 16 + lm] = acc1[rg];
        }
    }
}

// ---------------------------------------------------------------------------
extern "C" void kernel_launch(void* const* d_in, const int* in_sizes, int n_in,
                              void* d_out, int out_size, void* d_ws, size_t ws_size,
                              hipStream_t stream) {
    (void)in_sizes; (void)n_in; (void)out_size; (void)ws_size;

    const float* h0 = (const float*)d_in[0];   // [B, DH]
    const float* x  = (const float*)d_in[1];   // [T, B, DI]
    const float* a  = (const float*)d_in[2];   // [DH]
    const float* bm = (const float*)d_in[3];   // [DI, DH]
    const float* cm = (const float*)d_in[4];   // [DH, DO]

    float* out  = (float*)d_out;
    float* hfin = out;                         // [B, DH]
    float* y    = out + (size_t)B_ * DH_;      // [T, B, DO]

    float* r = (float*)d_ws;                   // [C, B, DH] (8 MB) — becomes Hst in-place
    unsigned short* bhi = (unsigned short*)(r + (size_t)C_ * B_ * DH_);
    unsigned short* be1 = bhi + 32768;
    unsigned short* be2 = be1 + 32768;
    unsigned short* cfr = be2 + 32768;
    unsigned short* Xm  = cfr + 32768;         // [C][3][4096] bf16 (1.5 MB)

    const size_t LDSZ_Y = (size_t)DH_ * XBSTR * 4;   // 69632 B

    k_frags<<<dim3(128), 256, 0, stream>>>(bm, cm, a, bhi, be1, be2, cfr);
    k_mom<<<dim3(C_, 16), 256, 0, stream>>>(x, Xm);
    k_rg<<<dim3(C_, 2), 512, 0, stream>>>(Xm, bhi, be1, be2, r);
    k_scan<<<dim3(B_), 512, 0, stream>>>(h0, a, r, hfin);
    k_y<<<dim3(C_, B_), 512, LDSZ_Y, stream>>>(x, a, bhi, cfr, r, y);
}

// Round 10
// 133.380 us; speedup vs baseline: 12.5446x; 1.0158x over previous
//
#include <hip/hip_runtime.h>
#include <stdint.h>

// Problem constants
#define T_  4096
#define B_  64
#define DI_ 64
#define DH_ 512
#define DO_ 64
#define L_  64          // chunk length
#define C_  (T_ / L_)   // 64 chunks

// k_y LDS: xb region 512 rows x 34 dwords (136 B; 64 bf16 + 8 B pad)
#define XBSTR 34

typedef __attribute__((ext_vector_type(8))) short bf16x8;
typedef __attribute__((ext_vector_type(4))) float f32x4;
typedef __attribute__((ext_vector_type(8))) float f32x8;
typedef __attribute__((ext_vector_type(8))) __bf16 bfv8;
typedef __attribute__((ext_vector_type(4))) __bf16 bfv4;

union U8 { uint4 q; bf16x8 v; bfv8 b; };
union U4 { uint2 d; bfv4 b; };

__device__ inline unsigned short f2b_rne(float f) {
    unsigned u = __float_as_uint(f);
    return (unsigned short)((u + 0x7fffu + ((u >> 16) & 1u)) >> 16);
}

// native convert 8 f32 -> bf16x8 (compiler emits v_cvt_pk_bf16_f32, RNE)
__device__ inline void cvt8n(const float4 v0, const float4 v1, U8& out) {
    const f32x8 f = {v0.x, v0.y, v0.z, v0.w, v1.x, v1.y, v1.z, v1.w};
    out.b = __builtin_convertvector(f, bfv8);
}

// ---------------------------------------------------------------------------
// k_frags: b -> bhi frags + u-weighted moment frags be1 = u*b, be2 = (u^2/2)*b
// (u = ln a per col h); c -> cfr frags. Layout: [kb][nt][lane][8]. (one-time)
// ---------------------------------------------------------------------------
__global__ __launch_bounds__(256) void k_frags(
    const float* __restrict__ bmat, const float* __restrict__ cmat,
    const float* __restrict__ a,
    unsigned short* __restrict__ bhi, unsigned short* __restrict__ be1,
    unsigned short* __restrict__ be2, unsigned short* __restrict__ cfr)
{
    const int t = blockIdx.x * 256 + threadIdx.x;   // 0..32767
    {
        const int j = t & 7, n = (t >> 3) & 15, g = (t >> 7) & 3;
        const int nt = (t >> 9) & 31, kb = (t >> 14) & 1;
        const int h = nt * 16 + n;
        const float v = bmat[(size_t)(kb * 32 + g * 8 + j) * DH_ + h];
        const float u = logf(a[h]);
        bhi[t] = f2b_rne(v);
        be1[t] = f2b_rne(v * u);
        be2[t] = f2b_rne(v * u * u * 0.5f);
    }
    {
        const int j = t & 7, n = (t >> 3) & 15, g = (t >> 7) & 3;
        const int nt = (t >> 9) & 3, kb = (t >> 11) & 15;
        float v = cmat[(size_t)(kb * 32 + g * 8 + j) * DO_ + nt * 16 + n];
        cfr[t] = f2b_rne(v);
    }
}

// ---------------------------------------------------------------------------
// k_mom: per-chunk moment reduction over x (streaming, memory-bound).
// X_k[c][k][bb*64+i] = sum_s (63-s)^k * x[c*64+s][bb][i], k = 0,1,2 (bf16).
// ---------------------------------------------------------------------------
__global__ __launch_bounds__(256) void k_mom(
    const float* __restrict__ x, unsigned short* __restrict__ Xm)
{
    const int c   = blockIdx.x;
    const int idx = blockIdx.y * 256 + threadIdx.x;   // (bb*64 + i)
    const float* xp = x + (size_t)c * 64 * 4096 + idx;

    float m0 = 0.f, m1 = 0.f, m2 = 0.f;
#pragma unroll
    for (int s = 0; s < 64; ++s) {
        const float v = xp[(size_t)s * 4096];
        const float t = (float)(63 - s);
        m0 += v;
        m1 = fmaf(t, v, m1);
        m2 = fmaf(t * t, v, m2);
    }
    __bf16* Xb = (__bf16*)Xm;
    Xb[(size_t)(c * 3 + 0) * 4096 + idx] = (__bf16)m0;
    Xb[(size_t)(c * 3 + 1) * 4096 + idx] = (__bf16)m1;
    Xb[(size_t)(c * 3 + 2) * 4096 + idx] = (__bf16)m2;
}

// ---------------------------------------------------------------------------
// k_rg: r[c][bb][h] = sum_k (u^k/k!)(X_k @ b)[h] as one GEMM, K=192 folded.
// ---------------------------------------------------------------------------
__global__ __launch_bounds__(512) void k_rg(
    const unsigned short* __restrict__ Xm,
    const unsigned short* __restrict__ bhi, const unsigned short* __restrict__ be1,
    const unsigned short* __restrict__ be2,
    float* __restrict__ r)
{
    const int c    = blockIdx.x;
    const int nh   = blockIdx.y;
    const int tid  = threadIdx.x;
    const int lane = tid & 63;
    const int w    = tid >> 6;
    const int lm   = lane & 15;
    const int lg   = lane >> 4;

    bf16x8 af[4][6];
#pragma unroll
    for (int mt = 0; mt < 4; ++mt)
#pragma unroll
        for (int kb = 0; kb < 6; ++kb) {
            const int mom = kb >> 1;
            af[mt][kb] = *(const bf16x8*)(Xm + (size_t)(c * 3 + mom) * 4096
                                          + (mt * 16 + lm) * 64 + (kb & 1) * 32 + lg * 8);
        }

    bf16x8 bfr[6][2];
#pragma unroll
    for (int kb = 0; kb < 6; ++kb) {
        const int mom = kb >> 1;
        const unsigned short* base = (mom == 0) ? bhi : (mom == 1) ? be1 : be2;
#pragma unroll
        for (int nt = 0; nt < 2; ++nt) {
            const int ntg = nh * 16 + w * 2 + nt;
            bfr[kb][nt] = *(const bf16x8*)(base + ((size_t)((kb & 1) * 32 + ntg) * 64 + lane) * 8);
        }
    }

    f32x4 acc[4][2];
#pragma unroll
    for (int mt = 0; mt < 4; ++mt)
#pragma unroll
        for (int nt = 0; nt < 2; ++nt) acc[mt][nt] = (f32x4){0.f, 0.f, 0.f, 0.f};

#pragma unroll
    for (int kb = 0; kb < 6; ++kb)
#pragma unroll
        for (int nt = 0; nt < 2; ++nt)
#pragma unroll
            for (int mt = 0; mt < 4; ++mt)
                acc[mt][nt] = __builtin_amdgcn_mfma_f32_16x16x32_bf16(af[mt][kb], bfr[kb][nt], acc[mt][nt], 0, 0, 0);

#pragma unroll
    for (int mt = 0; mt < 4; ++mt)
#pragma unroll
        for (int nt = 0; nt < 2; ++nt)
#pragma unroll
            for (int rg = 0; rg < 4; ++rg) {
                const int bb = mt * 16 + lg * 4 + rg;
                const int h  = nh * 256 + w * 32 + nt * 16 + lm;
                r[((size_t)c * B_ + bb) * DH_ + h] = acc[mt][nt][rg];
            }
}

// ---------------------------------------------------------------------------
// k_scan: sequential scan over chunk aggregates, IN PLACE (r becomes Hst).
// ---------------------------------------------------------------------------
__global__ __launch_bounds__(512) void k_scan(
    const float* __restrict__ h0, const float* __restrict__ a,
    float* __restrict__ r, float* __restrict__ hfin)
{
    const int bb  = blockIdx.x;
    const int hid = threadIdx.x;
    const size_t base = (size_t)bb * DH_ + hid;

    float rv[C_];
#pragma unroll
    for (int c = 0; c < C_; ++c) rv[c] = r[(size_t)c * B_ * DH_ + base];

    float h  = h0[base];
    float aL = a[hid];
#pragma unroll
    for (int q = 0; q < 6; ++q) aL = aL * aL;   // a^64

#pragma unroll
    for (int c = 0; c < C_; ++c) {
        r[(size_t)c * B_ * DH_ + base] = h;      // Hst[c] = state BEFORE chunk c
        h = fmaf(h, aL, rv[c]);
    }
    hfin[base] = h;
}

// ---------------------------------------------------------------------------
// k_y: per (chunk, batch) block, 512 threads, LDS 68 KB -> 2 blocks/CU.
//  ph2: xb = x @ b (1-term bf16 MFMA, native cvt); pack to LDS [hid][s].
//  cfr preload: wave role (mp = w>>2, oq = w&3) -> 16 frags/wave, PINNED via
//    asm volatile keep-alive before ph3's barrier (rule #17: barriers alone
//    don't stop the compiler sinking const loads).
//  ph3: wave-local xb read (no barrier), barrier, serial scan, native h store.
//  ph4: y = h @ c from register-resident cfr, setprio around MFMA cluster.
// ---------------------------------------------------------------------------
__global__ __launch_bounds__(512, 4) void k_y(
    const float* __restrict__ x, const float* __restrict__ a,
    const unsigned short* __restrict__ bhi, const unsigned short* __restrict__ cfr,
    const float* __restrict__ Hst, float* __restrict__ y)
{
    extern __shared__ unsigned lds[];               // 512*34*4 = 69632 B
    unsigned short* hb = (unsigned short*)lds;      // overlay: [64 s][512 hid^swz]

    const int c    = blockIdx.x;
    const int bb   = blockIdx.y;
    const int tid  = threadIdx.x;
    const int lane = tid & 63;
    const int w    = tid >> 6;
    const int lm   = lane & 15;
    const int lg   = lane >> 4;

    // early Hst prefetch (consumed in ph3)
    const float hstart = Hst[((size_t)c * B_ + bb) * DH_ + tid];

    // ---- ph2: xb = x @ b (1-term, hoisted loads) ----
    {
        bf16x8 bf[2][4];
#pragma unroll
        for (int kb = 0; kb < 2; ++kb)
#pragma unroll
            for (int ntl = 0; ntl < 4; ++ntl)
                bf[kb][ntl] = *(const bf16x8*)(bhi + ((size_t)(kb * 32 + w * 4 + ntl) * 64 + lane) * 8);

        float4 xv0[4][2], xv1[4][2];
#pragma unroll
        for (int mt = 0; mt < 4; ++mt)
#pragma unroll
            for (int kb = 0; kb < 2; ++kb) {
                const float* gp = x + (((size_t)(c * 64 + mt * 16 + lm)) * 64 + bb) * 64 + kb * 32 + lg * 8;
                xv0[mt][kb] = *(const float4*)gp;
                xv1[mt][kb] = *(const float4*)(gp + 4);
            }
        U8 xf[4][2];
#pragma unroll
        for (int mt = 0; mt < 4; ++mt)
#pragma unroll
            for (int kb = 0; kb < 2; ++kb)
                cvt8n(xv0[mt][kb], xv1[mt][kb], xf[mt][kb]);

        f32x4 acc[4][4];
#pragma unroll
        for (int mt = 0; mt < 4; ++mt)
#pragma unroll
            for (int nt = 0; nt < 4; ++nt) acc[mt][nt] = (f32x4){0.f, 0.f, 0.f, 0.f};

#pragma unroll
        for (int ntl = 0; ntl < 4; ++ntl)
#pragma unroll
            for (int kb = 0; kb < 2; ++kb)
#pragma unroll
                for (int mt = 0; mt < 4; ++mt)
                    acc[mt][ntl] = __builtin_amdgcn_mfma_f32_16x16x32_bf16(xf[mt][kb].v, bf[kb][ntl], acc[mt][ntl], 0, 0, 0);

        // pack 4 consecutive s (rg 0..3 at s0 = mt*16+lg*4) via native cvt, b64 write
#pragma unroll
        for (int mt = 0; mt < 4; ++mt)
#pragma unroll
            for (int ntl = 0; ntl < 4; ++ntl) {
                const int hid = (w * 4 + ntl) * 16 + lm;
                U4 t;
                t.b = __builtin_convertvector(acc[mt][ntl], bfv4);
                uint2* dst = (uint2*)(lds + (size_t)hid * XBSTR + mt * 8 + lg * 2);
                *dst = t.d;
            }
    }
    // NO barrier: ph3 reads only this wave's own rows; lgkmcnt ordering suffices.

    // ---- cfr preload for ph4 ----
    // ph4 wave role: mp = w>>2 (s-half), oq = w&3 (o-quarter, 16 wide)
    const int mp = w >> 2;
    const int oq = w & 3;
    bf16x8 cpre[16];
#pragma unroll
    for (int kb = 0; kb < 16; ++kb)
        cpre[kb] = *(const bf16x8*)(cfr + ((size_t)(kb * 4 + oq) * 64 + lane) * 8);
    // pin: force materialization here (compiler would otherwise sink these
    // const loads past the barrier into ph4 — R8 post-mortem, VGPR stayed 56)
#pragma unroll
    for (int kb = 0; kb < 16; ++kb)
        asm volatile("" :: "v"(cpre[kb]));

    // ---- ph3: per-hid serial scan ----
    {
        const int hid = tid;
        uint2 xr[16];
        const unsigned* rowp = lds + (size_t)hid * XBSTR;
#pragma unroll
        for (int j = 0; j < 16; ++j) xr[j] = *(const uint2*)(rowp + 2 * j);

        __syncthreads();   // all xb reads done before h overlay writes

        const float ah = a[hid];
        float h = hstart;
        __bf16* hbb = (__bf16*)hb;

#define STEP(xbits, sidx)                                                      \
        {                                                                      \
            h = fmaf(h, ah, __uint_as_float(xbits));                           \
            hbb[(sidx) * DH_ + (hid ^ (((sidx) & 7) << 3))] = (__bf16)h;       \
        }
#pragma unroll
        for (int j = 0; j < 16; ++j) {
            const unsigned ux = xr[j].x, uy = xr[j].y;
            STEP(ux << 16,          j * 4 + 0)
            STEP(ux & 0xffff0000u,  j * 4 + 1)
            STEP(uy << 16,          j * 4 + 2)
            STEP(uy & 0xffff0000u,  j * 4 + 3)
        }
#undef STEP
    }
    __syncthreads();

    // ---- ph4: y = h @ c (cfr in registers; 2 m-tiles x 1 o-quarter) ----
    {
        f32x4 acc0 = {0.f, 0.f, 0.f, 0.f};   // mt = mp*2
        f32x4 acc1 = {0.f, 0.f, 0.f, 0.f};   // mt = mp*2+1
        const int row0 = (mp * 2 + 0) * 16 + lm;
        const int row1 = (mp * 2 + 1) * 16 + lm;
        const int sw0 = (row0 & 7) << 3;
        const int sw1 = (row1 & 7) << 3;
        const unsigned short* hr0 = hb + row0 * DH_;
        const unsigned short* hr1 = hb + row1 * DH_;

        __builtin_amdgcn_s_setprio(1);
#pragma unroll
        for (int kb = 0; kb < 16; ++kb) {
            const int k0 = kb * 32 + lg * 8;
            const bf16x8 a0 = *(const bf16x8*)(hr0 + (k0 ^ sw0));
            const bf16x8 a1 = *(const bf16x8*)(hr1 + (k0 ^ sw1));
            acc0 = __builtin_amdgcn_mfma_f32_16x16x32_bf16(a0, cpre[kb], acc0, 0, 0, 0);
            acc1 = __builtin_amdgcn_mfma_f32_16x16x32_bf16(a1, cpre[kb], acc1, 0, 0, 0);
        }
        __builtin_amdgcn_s_setprio(0);

        // D layout: col = lm (o), row = lg*4 + rg (s within tile)
#pragma unroll
        for (int rg = 0; rg < 4; ++rg) {
            const int sr0 = (mp * 2 + 0) * 16 + lg * 4 + rg;
            const int sr1 = (mp * 2 + 1) * 16 + lg * 4 + rg;
            y[(((size_t)(c * 64 + sr0)) * 64 + bb) * 64 + oq * 16 + lm] = acc0[rg];
            y[(((size_t)(c * 64 + sr1)) * 64 + bb) * 64 + oq * 16 + lm] = acc1[rg];
        }
    }
}

// ---------------------------------------------------------------------------
extern "C" void kernel_launch(void* const* d_in, const int* in_sizes, int n_in,
                              void* d_out, int out_size, void* d_ws, size_t ws_size,
                              hipStream_t stream) {
    (void)in_sizes; (void)n_in; (void)out_size; (void)ws_size;

    const float* h0 = (const float*)d_in[0];   // [B, DH]
    const float* x  = (const float*)d_in[1];   // [T, B, DI]
    const float* a  = (const float*)d_in[2];   // [DH]
    const float* bm = (const float*)d_in[3];   // [DI, DH]
    const float* cm = (const float*)d_in[4];   // [DH, DO]

    float* out  = (float*)d_out;
    float* hfin = out;                         // [B, DH]
    float* y    = out + (size_t)B_ * DH_;      // [T, B, DO]

    float* r = (float*)d_ws;                   // [C, B, DH] (8 MB) — becomes Hst in-place
    unsigned short* bhi = (unsigned short*)(r + (size_t)C_ * B_ * DH_);
    unsigned short* be1 = bhi + 32768;
    unsigned short* be2 = be1 + 32768;
    unsigned short* cfr = be2 + 32768;
    unsigned short* Xm  = cfr + 32768;         // [C][3][4096] bf16 (1.5 MB)

    const size_t LDSZ_Y = (size_t)DH_ * XBSTR * 4;   // 69632 B

    k_frags<<<dim3(128), 256, 0, stream>>>(bm, cm, a, bhi, be1, be2, cfr);
    k_mom<<<dim3(C_, 16), 256, 0, stream>>>(x, Xm);
    k_rg<<<dim3(C_, 2), 512, 0, stream>>>(Xm, bhi, be1, be2, r);
    k_scan<<<dim3(B_), 512, 0, stream>>>(h0, a, r, hfin);
    k_y<<<dim3(C_, B_), 512, LDSZ_Y, stream>>>(x, a, bhi, cfr, r, y);
}